// Round 3
// baseline (346.540 us; speedup 1.0000x reference)
//
#include <hip/hip_runtime.h>

typedef unsigned int uint;
typedef unsigned char uchar;

#define NB_MAX 256      // max buckets
#define NPB_MAX 2048    // max nodes per bucket
#define GAGG_MAX 1024   // max agg blocks (pooling partial slots sized to this)

#if defined(__has_builtin)
#if __has_builtin(__builtin_amdgcn_cvt_pk_f32_fp8) && __has_builtin(__builtin_amdgcn_cvt_pk_fp8_f32)
#define HW_FP8 1
#endif
#endif

typedef __attribute__((ext_vector_type(2))) float v2f;

// ---------------- fp8 e4m3 codecs (internal z/h storage) ----------------
static __device__ __forceinline__ uint f2fp8_sw(float v) {
    v = fminf(fmaxf(v, -448.f), 448.f);
    uint u = __float_as_uint(v);
    uint s = (u >> 24) & 0x80u;
    uint mag = u & 0x7FFFFFFFu;
    uint r = mag + 0x7FFFFu + ((mag >> 20) & 1u);     // RNE to 3 mantissa bits
    if (r < 0x3C800000u) return s;                    // below 2^-6 -> ±0
    uint e8 = (r - 0x3C000000u) >> 20;
    return s | min(e8, 0x7Eu);
}
static __device__ __forceinline__ float fp82f(uint b) {
    uint mag = b & 0x7Fu;
    uint bits = ((b & 0x80u) << 24) | ((mag << 20) + 0x3C000000u);
    return mag ? __uint_as_float(bits) : 0.f;
}
static __device__ __forceinline__ void dec8(uint2 v, float* o) {
#ifdef HW_FP8
    v2f a = __builtin_amdgcn_cvt_pk_f32_fp8((int)v.x, false);
    v2f b = __builtin_amdgcn_cvt_pk_f32_fp8((int)v.x, true);
    v2f c = __builtin_amdgcn_cvt_pk_f32_fp8((int)v.y, false);
    v2f d = __builtin_amdgcn_cvt_pk_f32_fp8((int)v.y, true);
    o[0]=a.x; o[1]=a.y; o[2]=b.x; o[3]=b.y;
    o[4]=c.x; o[5]=c.y; o[6]=d.x; o[7]=d.y;
#else
    o[0]=fp82f(v.x&0xFF); o[1]=fp82f((v.x>>8)&0xFF); o[2]=fp82f((v.x>>16)&0xFF); o[3]=fp82f(v.x>>24);
    o[4]=fp82f(v.y&0xFF); o[5]=fp82f((v.y>>8)&0xFF); o[6]=fp82f((v.y>>16)&0xFF); o[7]=fp82f(v.y>>24);
#endif
}
static __device__ __forceinline__ uint2 enc8(const float* o) {
#ifdef HW_FP8
    int rx = __builtin_amdgcn_cvt_pk_fp8_f32(o[0], o[1], 0, false);
    rx = __builtin_amdgcn_cvt_pk_fp8_f32(o[2], o[3], rx, true);
    int ry = __builtin_amdgcn_cvt_pk_fp8_f32(o[4], o[5], 0, false);
    ry = __builtin_amdgcn_cvt_pk_fp8_f32(o[6], o[7], ry, true);
    return make_uint2((uint)rx, (uint)ry);
#else
    uint2 r;
    r.x = f2fp8_sw(o[0]) | (f2fp8_sw(o[1])<<8) | (f2fp8_sw(o[2])<<16) | (f2fp8_sw(o[3])<<24);
    r.y = f2fp8_sw(o[4]) | (f2fp8_sw(o[5])<<8) | (f2fp8_sw(o[6])<<16) | (f2fp8_sw(o[7])<<24);
    return r;
#endif
}

// ---------------- wave-level inclusive scan (64 lanes) ----------------
static __device__ __forceinline__ unsigned wave_incl_scan(unsigned v) {
    int lane = threadIdx.x & 63;
    #pragma unroll
    for (int d = 1; d < 64; d <<= 1) {
        unsigned t = (unsigned)__shfl_up((int)v, d, 64);
        if (lane >= d) v += t;
    }
    return v;
}

// exclusive block scan: in[0..n) -> out[0..n), n <= 2048, 256 threads, wscr = shared[4]
static __device__ void block_excl_scan(const uint* in, uint* out, int n, uint* wscr) {
    int tid = threadIdx.x;
    int lane = tid & 63, wid = tid >> 6;
    int base = tid * 8;
    uint v[8], pre[8], s = 0;
    #pragma unroll
    for (int k = 0; k < 8; k++) v[k] = (base + k < n) ? in[base + k] : 0u;
    #pragma unroll
    for (int k = 0; k < 8; k++) { pre[k] = s; s += v[k]; }
    uint is = wave_incl_scan(s);
    __syncthreads();
    if (lane == 63) wscr[wid] = is;
    __syncthreads();
    uint woff = 0;
    for (int wI = 0; wI < wid; wI++) woff += wscr[wI];
    uint excl = is - s + woff;
    #pragma unroll
    for (int k = 0; k < 8; k++) if (base + k < n) out[base + k] = excl + pre[k];
    __syncthreads();
}

// ---------------- phase 1: per-bucket edge & candidate histograms ----------------
__global__ __launch_bounds__(256) void bucket_hist_kernel(const int* src, const int* dst,
                                                          const int* nt, uint* bcnt, uint* bcand,
                                                          int E, int N, int NB, int shift) {
    __shared__ uint bh[NB_MAX], ch[NB_MAX];
    int tid = threadIdx.x;
    bh[tid] = 0; ch[tid] = 0;
    __syncthreads();
    int gs = gridDim.x * 256;
    for (int i = blockIdx.x * 256 + tid; i < E; i += gs) {
        int d = dst[i], s = src[i];
        if ((uint)d < (uint)N && (uint)s < (uint)N) atomicAdd(&bh[d >> shift], 1u);
    }
    for (int i = blockIdx.x * 256 + tid; i < N; i += gs) {
        if (nt[i] == 0) atomicAdd(&ch[i >> shift], 1u);
    }
    __syncthreads();
    if (bh[tid]) atomicAdd(&bcnt[tid], bh[tid]);
    if (ch[tid]) atomicAdd(&bcand[tid], ch[tid]);
}

// ---------------- phase 2: partition edges into bucket-contiguous packed staging ----------------
// staging entry: (dst_local << 17) | src   (requires N < 2^17, shift <= 15)
__global__ __launch_bounds__(256) void partition_kernel(const int* src, const int* dst,
                                                        const uint* bcnt, uint* alloc0,
                                                        uint* staging, int E, int N, int shift) {
    __shared__ uint bbase_s[NB_MAX];
    __shared__ uint lh[NB_MAX], gb[NB_MAX];
    __shared__ uint ws4[4];
    int tid = threadIdx.x;
    int lane = tid & 63, wid = tid >> 6;
    uint a = bcnt[tid];
    uint ia = wave_incl_scan(a);
    if (lane == 63) ws4[wid] = ia;
    __syncthreads();
    uint off = 0;
    for (int wI = 0; wI < wid; wI++) off += ws4[wI];
    bbase_s[tid] = ia - a + off;
    lh[tid] = 0;
    __syncthreads();
    int base = blockIdx.x * 2048;
    uint mask = (1u << shift) - 1u;
    int breg[8];
    uint rreg[8], pk8[8];
    #pragma unroll
    for (int k = 0; k < 8; k++) {
        int e = base + k * 256 + tid;
        breg[k] = -1;
        if (e < E) {
            int s = src[e], d = dst[e];
            if ((uint)d < (uint)N && (uint)s < (uint)N) {
                int b = d >> shift;
                pk8[k] = (((uint)d & mask) << 17) | (uint)s;
                breg[k] = b;
                rreg[k] = atomicAdd(&lh[b], 1u);
            }
        }
    }
    __syncthreads();
    gb[tid] = lh[tid] ? (bbase_s[tid] + atomicAdd(&alloc0[tid], lh[tid])) : 0u;
    __syncthreads();
    #pragma unroll
    for (int k = 0; k < 8; k++) {
        if (breg[k] >= 0)
            staging[gb[breg[k]] + rreg[k]] = pk8[k];
    }
}

// ---------------- phase 3: per-bucket counting sort + csr_off/dinv/cand_pos + xs rows ----------------
// xs row = (x*dinv, dinv) so layer-1 agg also produces S = dinv_i + sum dinv_j in lane c4==3
__global__ __launch_bounds__(256) void local_csr_kernel(const uint* staging, const uint* bcnt,
                                                        const uint* bcand, const int* nt,
                                                        const float* x,
                                                        int* csr_src, uint* csr_off, uint* cand_pos,
                                                        float* dinv, float4* xs,
                                                        int N, int shift, int NB) {
    __shared__ uint deg[NPB_MAX];
    __shared__ uint ofs[NPB_MAX];
    __shared__ uint ws4[4];
    __shared__ uint sb[4];        // ebase, eend, cb
    int b = blockIdx.x, tid = threadIdx.x;
    int lane = tid & 63, wid = tid >> 6;
    uint a = bcnt[tid];
    uint ia = wave_incl_scan(a);
    if (lane == 63) ws4[wid] = ia;
    __syncthreads();
    uint off = 0;
    for (int wI = 0; wI < wid; wI++) off += ws4[wI];
    if (tid == b) { sb[0] = ia - a + off; sb[1] = ia + off; }
    __syncthreads();
    uint c = bcand[tid];
    uint ic = wave_incl_scan(c);
    if (lane == 63) ws4[wid] = ic;
    __syncthreads();
    uint offc = 0;
    for (int wI = 0; wI < wid; wI++) offc += ws4[wI];
    if (tid == b) sb[2] = ic - c + offc;
    __syncthreads();
    uint ebase = sb[0], eend = sb[1], cb = sb[2];
    int nbase = b << shift;
    int ncount = min(1 << shift, N - nbase);
    for (int i = tid; i < ncount; i += 256) deg[i] = 0;
    __syncthreads();
    for (uint p = ebase + tid; p < eend; p += 256)
        atomicAdd(&deg[staging[p] >> 17], 1u);
    __syncthreads();
    block_excl_scan(deg, ofs, ncount, ws4);
    for (int i = tid; i < ncount; i += 256)
        csr_off[nbase + i] = ebase + ofs[i];
    if (b == NB - 1 && tid == 0) csr_off[N] = eend;
    // fused dinv + xs = (x * dinv, dinv)  (deg still intact)
    for (int i = tid; i < ncount; i += 256) {
        int g = nbase + i;
        float di = rsqrtf((float)(deg[i] + 1u));   // +1 self loop
        dinv[g] = di;
        xs[g] = make_float4(x[3*g] * di, x[3*g+1] * di, x[3*g+2] * di, di);
    }
    __syncthreads();
    for (int i = tid; i < ncount; i += 256) deg[i] = 0;   // reuse as running counters
    __syncthreads();
    for (uint p = ebase + tid; p < eend; p += 256) {
        uint pkv = staging[p];
        uint dl = pkv >> 17;
        uint pos = ebase + ofs[dl] + atomicAdd(&deg[dl], 1u);
        csr_src[pos] = (int)(pkv & 0x1FFFFu);
    }
    __syncthreads();
    for (int i = tid; i < ncount; i += 256) deg[i] = (nt[nbase + i] == 0) ? 1u : 0u;
    __syncthreads();
    block_excl_scan(deg, ofs, ncount, ws4);
    for (int i = tid; i < ncount; i += 256) cand_pos[nbase + i] = cb + ofs[i];
}

// ---------------- layer-1 aggregate: rank-3 trick, block-level work-stealing chunks ----------------
// Writes hb = fp8(dinv_i * h1_i) (pre-scaled for next layer's linear aggregation),
// Sbuf[i] = dinv_i + sum_j dinv_j (from xs.w channel), stats over RAW h1.
__global__ __launch_bounds__(256) void agg1_kernel(const float* xs, const int* csr_src,
                                                   const uint* csr_off, const float* dinv,
                                                   const float* W1, const float* b1, uchar* hb,
                                                   float* Sbuf, int n,
                                                   float* stats_sum, float* stats_sq,
                                                   uint* gt) {
    const int tid = threadIdx.x;
    const int wave = tid >> 6;
    const int lane = tid & 63;
    const int c4 = lane & 3;
    const int slot = lane >> 2;
    const int qlead = lane & ~3;
    __shared__ float W1s[96];
    __shared__ uint s_lt, s_chunk;
    if (tid < 96) W1s[tid] = W1[tid];
    float bv[8];
    #pragma unroll
    for (int j = 0; j < 8; j++) bv[j] = b1[c4 * 8 + j];
    float bs[8], bq[8];
    #pragma unroll
    for (int j = 0; j < 8; j++) { bs[j] = 0.f; bq[j] = 0.f; }
    __syncthreads();
    while (true) {
        if (tid == 0) s_chunk = atomicAdd(gt, 1u);
        __syncthreads();
        uint cbase = s_chunk * 128u;
        if (cbase >= (uint)n) break;
        uint avail = min((uint)n - cbase, 128u);
        if (tid == 0) s_lt = 0u;
        __syncthreads();
        while (true) {
            uint li = 0;
            if (c4 == 0) li = atomicAdd(&s_lt, 1u);
            li = (uint)__shfl((int)li, qlead, 64);
            if (li >= avail) break;
            uint node = cbase + li;
            uint s = csr_off[node], e = csr_off[node + 1];
            float acc = xs[(size_t)node * 4 + c4];     // self loop (xs has dinv folded; .w = dinv)
            for (uint p = s; p < e; p += 8) {
                uint idx[8];
                float wg[8];
                #pragma unroll
                for (int j = 0; j < 8; j++) {
                    uint q = p + (uint)j;
                    uint qc = min(q, e - 1u);
                    idx[j] = (uint)csr_src[qc];
                    wg[j] = (q < e) ? 1.f : 0.f;
                }
                #pragma unroll
                for (int j = 0; j < 8; j++)
                    acc = fmaf(wg[j], xs[(size_t)idx[j] * 4 + c4], acc);
            }
            if (c4 == 3) Sbuf[node] = acc;             // S_i (raw sum of dinv over closed nbhd)
            float di = dinv[node];
            float u = di * acc;
            float u0 = __shfl(u, qlead, 64);
            float u1 = __shfl(u, qlead + 1, 64);
            float u2 = __shfl(u, qlead + 2, 64);
            float hv[8], sv[8];
            #pragma unroll
            for (int j = 0; j < 8; j++) {
                int ch = c4 * 8 + j;
                float o = u0 * W1s[ch] + u1 * W1s[32 + ch] + u2 * W1s[64 + ch] + bv[j];
                hv[j] = fmaxf(o, 0.f);
                sv[j] = di * hv[j];                    // pre-scaled storage
            }
            *(uint2*)(hb + (size_t)node * 32 + c4 * 8) = enc8(sv);
            #pragma unroll
            for (int j = 0; j < 8; j++) { bs[j] += hv[j]; bq[j] += hv[j] * hv[j]; }
        }
        __syncthreads();
    }
    #pragma unroll
    for (int m = 4; m < 64; m <<= 1) {
        #pragma unroll
        for (int j = 0; j < 8; j++) {
            bs[j] += __shfl_xor(bs[j], m, 64);
            bq[j] += __shfl_xor(bq[j], m, 64);
        }
    }
    __shared__ float ssum[4][32], ssq[4][32];
    if (slot == 0) {
        #pragma unroll
        for (int j = 0; j < 8; j++) { ssum[wave][c4 * 8 + j] = bs[j]; ssq[wave][c4 * 8 + j] = bq[j]; }
    }
    __syncthreads();
    if (tid < 32) {
        atomicAdd(&stats_sum[tid], ssum[0][tid] + ssum[1][tid] + ssum[2][tid] + ssum[3][tid]);
        atomicAdd(&stats_sq[tid],  ssq[0][tid] + ssq[1][tid] + ssq[2][tid] + ssq[3][tid]);
    }
}

// ---------------- layer 2: aggregate + BN1-fold + W2, pre-scaled fp8 out + BN stats ----------------
__global__ __launch_bounds__(256) void aggbn2_kernel(const uchar* hin, const int* csr_src,
                                                     const uint* csr_off, const float* dinv,
                                                     const float* Sbuf,
                                                     const float* stats_sum, const float* stats_sq,
                                                     const float* g, const float* be,
                                                     const float* W, const float* bias,
                                                     uchar* hout, int n, float inv_n,
                                                     float* osum, float* osq, uint* gt) {
    const int tid = threadIdx.x;
    const int wave = tid >> 6;
    const int lane = tid & 63;
    const int c4 = lane & 3;
    const int slot = lane >> 2;
    const int qlead = lane & ~3;
    __shared__ float Ws[1024];
    __shared__ float cs[32], a_s[32], d_s[32];
    __shared__ uint s_lt, s_chunk;
    if (tid < 32) {
        float mu = stats_sum[tid] * inv_n;
        float var = fmaxf(stats_sq[tid] * inv_n - mu * mu, 0.f);
        float a = g[tid] * rsqrtf(var + 1e-5f);
        a_s[tid] = a;
        d_s[tid] = be[tid] - mu * a;
    }
    __syncthreads();
    for (int t = tid; t < 1024; t += 256) Ws[t] = a_s[t >> 5] * W[t];
    if (tid < 32) {
        float c = 0.f;
        for (int k = 0; k < 32; k++) c += d_s[k] * W[k * 32 + tid];
        cs[tid] = c;
    }
    float bv[8];
    #pragma unroll
    for (int j = 0; j < 8; j++) bv[j] = bias[c4 * 8 + j];
    float bs[8], bq[8];
    #pragma unroll
    for (int j = 0; j < 8; j++) { bs[j] = 0.f; bq[j] = 0.f; }
    __syncthreads();
    while (true) {
        if (tid == 0) s_chunk = atomicAdd(gt, 1u);
        __syncthreads();
        uint cbase = s_chunk * 128u;
        if (cbase >= (uint)n) break;
        uint avail = min((uint)n - cbase, 128u);
        if (tid == 0) s_lt = 0u;
        __syncthreads();
        while (true) {
            uint li = 0;
            if (c4 == 0) li = atomicAdd(&s_lt, 1u);
            li = (uint)__shfl((int)li, qlead, 64);
            if (li >= avail) break;
            uint node = cbase + li;
            uint s = csr_off[node], e = csr_off[node + 1];
            float acc[8];
            dec8(*(const uint2*)(hin + (size_t)node * 32 + c4 * 8), acc);   // self (pre-scaled)
            for (uint p = s; p < e; p += 8) {
                uint idx[8];
                float wg[8];
                #pragma unroll
                for (int j = 0; j < 8; j++) {
                    uint q = p + (uint)j;
                    uint qc = min(q, e - 1u);
                    idx[j] = (uint)csr_src[qc];
                    wg[j] = (q < e) ? 1.f : 0.f;
                }
                #pragma unroll
                for (int j = 0; j < 8; j++) {
                    float t[8];
                    dec8(*(const uint2*)(hin + (size_t)idx[j] * 32 + c4 * 8), t);
                    #pragma unroll
                    for (int cI = 0; cI < 8; cI++) acc[cI] = fmaf(wg[j], t[cI], acc[cI]);
                }
            }
            // gather full 32-channel H_i across the quad (32 shuffles)
            float af[32];
            #pragma unroll
            for (int cc = 0; cc < 4; cc++) {
                #pragma unroll
                for (int r = 0; r < 8; r++)
                    af[cc * 8 + r] = __shfl(acc[r], qlead + cc, 64);
            }
            float di = dinv[node];
            float Sv = Sbuf[node];
            float hv[8], sv[8];
            #pragma unroll
            for (int jj = 0; jj < 8; jj++) {
                int j = c4 * 8 + jj;
                float t = cs[j] * Sv;
                #pragma unroll
                for (int k = 0; k < 32; k++) t = fmaf(Ws[k * 32 + j], af[k], t);
                hv[jj] = fmaxf(fmaf(di, t, bv[jj]), 0.f);
                sv[jj] = di * hv[jj];                  // pre-scale for layer 3
            }
            *(uint2*)(hout + (size_t)node * 32 + c4 * 8) = enc8(sv);
            #pragma unroll
            for (int jj = 0; jj < 8; jj++) { bs[jj] += hv[jj]; bq[jj] += hv[jj] * hv[jj]; }
        }
        __syncthreads();
    }
    #pragma unroll
    for (int m = 4; m < 64; m <<= 1) {
        #pragma unroll
        for (int j = 0; j < 8; j++) {
            bs[j] += __shfl_xor(bs[j], m, 64);
            bq[j] += __shfl_xor(bq[j], m, 64);
        }
    }
    __shared__ float ssum[4][32], ssq[4][32];
    if (slot == 0) {
        #pragma unroll
        for (int j = 0; j < 8; j++) { ssum[wave][c4 * 8 + j] = bs[j]; ssq[wave][c4 * 8 + j] = bq[j]; }
    }
    __syncthreads();
    if (tid < 32) {
        atomicAdd(&osum[tid], ssum[0][tid] + ssum[1][tid] + ssum[2][tid] + ssum[3][tid]);
        atomicAdd(&osq[tid],  ssq[0][tid] + ssq[1][tid] + ssq[2][tid] + ssq[3][tid]);
    }
}

// ---------------- layer 3 + heads, fully fused ----------------
// Aggregate + BN2-fold + W3 -> h3 in registers; inline candidate scoring; inline
// per-block online-softmax pooling partials; last block combines + graph head.
// h3 is never written to memory.
__global__ __launch_bounds__(256) void aggbn3_kernel(const uchar* hin, const int* csr_src,
                                                     const uint* csr_off, const float* dinv,
                                                     const float* Sbuf,
                                                     const float* stats_sum, const float* stats_sq,
                                                     const float* g, const float* be,
                                                     const float* W, const float* bias,
                                                     const int* nt, const uint* cand_pos,
                                                     const float* Wc1, const float* bc1,
                                                     const float* Wc2, const float* bc2,
                                                     const float* Wd1, const float* bd1,
                                                     const float* Wd2, const float* bd2,
                                                     float* blkM, float* blkZ, float* blkG,
                                                     uint* ticket, float* out,
                                                     int n, int C, float inv_n, uint* gt) {
    const int tid = threadIdx.x;
    const int wave = tid >> 6;
    const int lane = tid & 63;
    const int c4 = lane & 3;
    const int qlead = lane & ~3;
    __shared__ float Ws[1024];
    __shared__ float cs[32], a_s[32], d_s[32];
    __shared__ float W1h[512], b1h[16], W2h[16];
    __shared__ float pM[4], pZ[4], pgs[4][32];
    __shared__ float red[8][32], mred[4], geS[32], ttS[16];
    __shared__ uint s_lt, s_chunk;
    __shared__ int lastflag;
    if (tid < 32) {
        float mu = stats_sum[tid] * inv_n;
        float var = fmaxf(stats_sq[tid] * inv_n - mu * mu, 0.f);
        float a = g[tid] * rsqrtf(var + 1e-5f);
        a_s[tid] = a;
        d_s[tid] = be[tid] - mu * a;
    }
    __syncthreads();
    for (int t = tid; t < 1024; t += 256) Ws[t] = a_s[t >> 5] * W[t];
    for (int t = tid; t < 512; t += 256) W1h[t] = Wc1[t];
    if (tid < 32) {
        float c = 0.f;
        for (int k = 0; k < 32; k++) c += d_s[k] * W[k * 32 + tid];
        cs[tid] = c;
    }
    if (tid < 16) { b1h[tid] = bc1[tid]; W2h[tid] = Wc2[tid]; }
    float bv[8];
    #pragma unroll
    for (int j = 0; j < 8; j++) bv[j] = bias[c4 * 8 + j];
    // online-softmax pooling state (per lane; M/Z duplicated across the quad)
    float M = -3.0e38f, Zl = 0.f, pg[8];
    #pragma unroll
    for (int j = 0; j < 8; j++) pg[j] = 0.f;
    const float bc2v = bc2[0];
    __syncthreads();
    while (true) {
        if (tid == 0) s_chunk = atomicAdd(gt, 1u);
        __syncthreads();
        uint cbase = s_chunk * 128u;
        if (cbase >= (uint)n) break;
        uint avail = min((uint)n - cbase, 128u);
        if (tid == 0) s_lt = 0u;
        __syncthreads();
        while (true) {
            uint li = 0;
            if (c4 == 0) li = atomicAdd(&s_lt, 1u);
            li = (uint)__shfl((int)li, qlead, 64);
            if (li >= avail) break;
            uint node = cbase + li;
            uint s = csr_off[node], e = csr_off[node + 1];
            float acc[8];
            dec8(*(const uint2*)(hin + (size_t)node * 32 + c4 * 8), acc);   // self (pre-scaled)
            for (uint p = s; p < e; p += 8) {
                uint idx[8];
                float wg[8];
                #pragma unroll
                for (int j = 0; j < 8; j++) {
                    uint q = p + (uint)j;
                    uint qc = min(q, e - 1u);
                    idx[j] = (uint)csr_src[qc];
                    wg[j] = (q < e) ? 1.f : 0.f;
                }
                #pragma unroll
                for (int j = 0; j < 8; j++) {
                    float t[8];
                    dec8(*(const uint2*)(hin + (size_t)idx[j] * 32 + c4 * 8), t);
                    #pragma unroll
                    for (int cI = 0; cI < 8; cI++) acc[cI] = fmaf(wg[j], t[cI], acc[cI]);
                }
            }
            float af[32];
            #pragma unroll
            for (int cc = 0; cc < 4; cc++) {
                #pragma unroll
                for (int r = 0; r < 8; r++)
                    af[cc * 8 + r] = __shfl(acc[r], qlead + cc, 64);
            }
            float di = dinv[node];
            float Sv = Sbuf[node];
            float hv[8];
            #pragma unroll
            for (int jj = 0; jj < 8; jj++) {
                int j = c4 * 8 + jj;
                float t = cs[j] * Sv;
                #pragma unroll
                for (int k = 0; k < 32; k++) t = fmaf(Ws[k * 32 + j], af[k], t);
                hv[jj] = fmaxf(fmaf(di, t, bv[jj]), 0.f);
            }
            // ---- inline pooling (online softmax over rowsum) ----
            float rs = ((hv[0] + hv[1]) + (hv[2] + hv[3])) + ((hv[4] + hv[5]) + (hv[6] + hv[7]));
            rs += __shfl_xor(rs, 1, 64);
            rs += __shfl_xor(rs, 2, 64);               // full row sum in all 4 quad lanes
            if (rs > M) {
                float f = __expf(M - rs);
                #pragma unroll
                for (int j = 0; j < 8; j++) pg[j] *= f;
                Zl *= f;
                M = rs;
            }
            float wgt = __expf(rs - M);
            #pragma unroll
            for (int j = 0; j < 8; j++) pg[j] = fmaf(hv[j], wgt, pg[j]);
            Zl += wgt;
            // ---- inline candidate scoring (uses unquantized h3) ----
            if (nt[node] == 0) {
                float pu[16];
                #pragma unroll
                for (int j = 0; j < 16; j++) {
                    float t = 0.f;
                    #pragma unroll
                    for (int jj = 0; jj < 8; jj++)
                        t = fmaf(hv[jj], W1h[(c4 * 8 + jj) * 16 + j], t);
                    pu[j] = t;
                }
                #pragma unroll
                for (int j = 0; j < 16; j++) {
                    pu[j] += __shfl_xor(pu[j], 1, 64);
                    pu[j] += __shfl_xor(pu[j], 2, 64);
                }
                if (c4 == 0) {
                    float sc = bc2v;
                    #pragma unroll
                    for (int j = 0; j < 16; j++)
                        sc += fmaxf(pu[j] + b1h[j], 0.f) * W2h[j];
                    sc = fminf(fmaxf(sc, -1000.f), 1000.f);
                    uint pp = cand_pos[node];
                    if (pp < (uint)C) {
                        out[pp] = sc;
                        out[C + 1 + pp] = (float)node;
                    }
                }
            }
        }
        __syncthreads();
    }
    // ---- block-level pooling reduce: combine across slots (16 quads / wave) ----
    #pragma unroll
    for (int m = 4; m < 64; m <<= 1) {
        float Mo = __shfl_xor(M, m, 64);
        float Zo = __shfl_xor(Zl, m, 64);
        float Mn = fmaxf(M, Mo);
        float fa = __expf(M - Mn), fb = __expf(Mo - Mn);
        #pragma unroll
        for (int j = 0; j < 8; j++) {
            float po = __shfl_xor(pg[j], m, 64);
            pg[j] = pg[j] * fa + po * fb;
        }
        Zl = Zl * fa + Zo * fb;
        M = Mn;
    }
    if ((lane >> 2) == 0) {                    // lanes 0..3 hold full-wave combined state
        if (c4 == 0) { pM[wave] = M; pZ[wave] = Zl; }
        #pragma unroll
        for (int j = 0; j < 8; j++) pgs[wave][c4 * 8 + j] = pg[j];
    }
    __syncthreads();
    if (tid < 32) {
        float Mn = fmaxf(fmaxf(pM[0], pM[1]), fmaxf(pM[2], pM[3]));
        float a = 0.f;
        #pragma unroll
        for (int wv = 0; wv < 4; wv++) a += pgs[wv][tid] * __expf(pM[wv] - Mn);
        __hip_atomic_store(&blkG[(size_t)blockIdx.x * 32 + tid], a, __ATOMIC_RELAXED, __HIP_MEMORY_SCOPE_AGENT);
        if (tid == 0) {
            float Zt = 0.f;
            #pragma unroll
            for (int wv = 0; wv < 4; wv++) Zt += pZ[wv] * __expf(pM[wv] - Mn);
            __hip_atomic_store(&blkM[blockIdx.x], Mn, __ATOMIC_RELAXED, __HIP_MEMORY_SCOPE_AGENT);
            __hip_atomic_store(&blkZ[blockIdx.x], Zt, __ATOMIC_RELAXED, __HIP_MEMORY_SCOPE_AGENT);
        }
    }
    __syncthreads();
    if (tid == 0) {
        __threadfence();
        uint old = atomicAdd(ticket, 1u);
        lastflag = (old == gridDim.x - 1) ? 1 : 0;
    }
    __syncthreads();
    if (!lastflag) return;
    // ---- last block: combine per-block partials + graph head ----
    __threadfence();
    int NBLK = gridDim.x;
    float lm = -3.0e38f;
    for (int b = tid; b < NBLK; b += 256)
        lm = fmaxf(lm, __hip_atomic_load(&blkM[b], __ATOMIC_RELAXED, __HIP_MEMORY_SCOPE_AGENT));
    #pragma unroll
    for (int m = 1; m < 64; m <<= 1) lm = fmaxf(lm, __shfl_xor(lm, m, 64));
    if ((tid & 63) == 0) mred[tid >> 6] = lm;
    __syncthreads();
    float Mg = fmaxf(fmaxf(mred[0], mred[1]), fmaxf(mred[2], mred[3]));
    int lane32 = tid & 31, grp8 = tid >> 5;
    float a = 0.f, z = 0.f;
    for (int b = grp8; b < NBLK; b += 8) {
        float f = __expf(__hip_atomic_load(&blkM[b], __ATOMIC_RELAXED, __HIP_MEMORY_SCOPE_AGENT) - Mg);
        a += __hip_atomic_load(&blkG[(size_t)b * 32 + lane32], __ATOMIC_RELAXED, __HIP_MEMORY_SCOPE_AGENT) * f;
        if (lane32 == 0) z += __hip_atomic_load(&blkZ[b], __ATOMIC_RELAXED, __HIP_MEMORY_SCOPE_AGENT) * f;
    }
    red[grp8][lane32] = a;
    __syncthreads();
    if (tid < 32) {
        float t = 0.f;
        #pragma unroll
        for (int gI = 0; gI < 8; gI++) t += red[gI][tid];
        geS[tid] = t;
    }
    // Z reduce: lane32==0 values live at tid = grp8*32
    if (tid < 8) red[0][tid] = (tid == 0) ? z : 0.f;   // placeholder; fixed below
    __syncthreads();
    // recompute Z properly: threads with lane32==0 wrote z in registers; gather via shared
    if (lane32 == 0) mred[0] = 0.f;
    __syncthreads();
    if (lane32 == 0) atomicAdd(&mred[0], z);
    __syncthreads();
    float Zv = fmaxf(mred[0], 1e-30f);
    if (tid < 32) geS[tid] /= Zv;
    __syncthreads();
    if (tid < 16) {
        float s = bd1[tid];
        for (int k = 0; k < 32; k++) s += geS[k] * Wd1[k * 16 + tid];
        ttS[tid] = fmaxf(s, 0.f);
    }
    __syncthreads();
    if (tid == 0) {
        float s = bd2[0];
        for (int j = 0; j < 16; j++) s += ttS[j] * Wd2[j];
        out[C] = fminf(fmaxf(s, -1000.f), 1000.f);
    }
}

// ---------------- host launch ----------------
extern "C" void kernel_launch(void* const* d_in, const int* in_sizes, int n_in,
                              void* d_out, int out_size, void* d_ws, size_t ws_size,
                              hipStream_t stream) {
    const float* x   = (const float*)d_in[0];
    const int*   ei  = (const int*)d_in[1];
    const int*   nt  = (const int*)d_in[2];
    const float* W1  = (const float*)d_in[3];  const float* b1  = (const float*)d_in[4];
    const float* W2  = (const float*)d_in[5];  const float* b2  = (const float*)d_in[6];
    const float* W3  = (const float*)d_in[7];  const float* b3  = (const float*)d_in[8];
    const float* g1  = (const float*)d_in[9];  const float* be1 = (const float*)d_in[10];
    const float* g2  = (const float*)d_in[11]; const float* be2 = (const float*)d_in[12];
    const float* Wc1 = (const float*)d_in[13]; const float* bc1 = (const float*)d_in[14];
    const float* Wc2 = (const float*)d_in[15]; const float* bc2 = (const float*)d_in[16];
    const float* Wd1 = (const float*)d_in[17]; const float* bd1 = (const float*)d_in[18];
    const float* Wd2 = (const float*)d_in[19]; const float* bd2 = (const float*)d_in[20];

    const int N = in_sizes[0] / 3;
    const int E = in_sizes[1] / 2;
    const int C = (out_size - 1) / 2;
    const int* e_src = ei;
    const int* e_dst = ei + E;
    float* out = (float*)d_out;

    // bucket geometry: nodes/bucket = 1<<shift, NB <= 256 (packing needs N < 2^17)
    int shift = 9;
    while (((N + (1 << shift) - 1) >> shift) > NB_MAX) shift++;
    const int NB = (N + (1 << shift) - 1) >> shift;

    // ---- workspace carve-up (~14.2 MB) ----
    char* w = (char*)d_ws;
    auto alloc = [&](size_t bytes) { void* p = (void*)w; w += (bytes + 255) & ~(size_t)255; return p; };
    float*    stats  = (float*)alloc(256 * 4);     // zeroed
    uint*     bcnt   = (uint*)alloc(NB_MAX * 4);   // zeroed
    uint*     bcand  = (uint*)alloc(NB_MAX * 4);   // zeroed
    uint*     alloc0 = (uint*)alloc(NB_MAX * 4);   // zeroed
    size_t zero_bytes = (size_t)((char*)w - (char*)stats);
    float*    dinv   = (float*)alloc((size_t)N * 4);
    uint*     csr_off= (uint*)alloc((size_t)(N + 1) * 4);
    uint*     cand_pos=(uint*)alloc((size_t)N * 4);
    float*    Sbuf   = (float*)alloc((size_t)N * 4);
    float*    blkM   = (float*)alloc(GAGG_MAX * 4);
    float*    blkZ   = (float*)alloc(GAGG_MAX * 4);
    float*    blkG   = (float*)alloc((size_t)GAGG_MAX * 32 * 4);
    int*      csr_src= (int*)alloc((size_t)E * 4);
    uint*     staging= (uint*)alloc((size_t)E * 4);
    uchar*    zb     = (uchar*)alloc((size_t)N * 32);
    uchar*    hb     = (uchar*)alloc((size_t)N * 32);
    // xs (N*16B float4) aliases zb (dead until aggbn2 writes h2 into zb)
    float4*   xs     = (float4*)zb;

    float* sum1 = stats;       float* sq1 = stats + 32;
    float* sum2 = stats + 64;  float* sq2 = stats + 96;
    uint* ticket = (uint*)(stats + 162);
    uint* gt1 = (uint*)(stats + 163);
    uint* gt2 = (uint*)(stats + 164);
    uint* gt3 = (uint*)(stats + 165);

    hipMemsetAsync(stats, 0, zero_bytes, stream);

    const int gPar = (E + 2047) / 2048;
    int gAgg = (N + 127) / 128;
    if (gAgg > GAGG_MAX) gAgg = GAGG_MAX;          // work stealing caps stragglers
    const float inv_n = 1.0f / (float)N;

    // ---- CSR build (XCD-local two-phase counting sort, packed staging) ----
    hipLaunchKernelGGL(bucket_hist_kernel, dim3(784), dim3(256), 0, stream, e_src, e_dst, nt, bcnt, bcand, E, N, NB, shift);
    hipLaunchKernelGGL(partition_kernel, dim3(gPar), dim3(256), 0, stream, e_src, e_dst, bcnt, alloc0, staging, E, N, shift);
    hipLaunchKernelGGL(local_csr_kernel, dim3(NB), dim3(256), 0, stream, staging, bcnt, bcand, nt,
                       x, csr_src, csr_off, cand_pos, dinv, xs, N, shift, NB);

    // ---- layer 1 (rank-3 aggregation + fused W1; writes pre-scaled h1 + S) ----
    hipLaunchKernelGGL(agg1_kernel, dim3(gAgg), dim3(256), 0, stream, (const float*)xs, csr_src, csr_off,
                       dinv, W1, b1, hb, Sbuf, N, sum1, sq1, gt1);

    // ---- layer 2: aggregate + BN1-fold + W2 ----
    hipLaunchKernelGGL(aggbn2_kernel, dim3(gAgg), dim3(256), 0, stream, hb, csr_src, csr_off,
                       dinv, Sbuf, sum1, sq1, g1, be1, W2, b2, zb, N, inv_n,
                       sum2, sq2, gt2);

    // ---- layer 3 + heads fully fused (h3 never hits memory) ----
    hipLaunchKernelGGL(aggbn3_kernel, dim3(gAgg), dim3(256), 0, stream, zb, csr_src, csr_off,
                       dinv, Sbuf, sum2, sq2, g2, be2, W3, b3,
                       nt, cand_pos, Wc1, bc1, Wc2, bc2, Wd1, bd1, Wd2, bd2,
                       blkM, blkZ, blkG, ticket, out, N, C, inv_n, gt3);
}

// Round 4
// 329.437 us; speedup vs baseline: 1.0519x; 1.0519x over previous
//
#include <hip/hip_runtime.h>

typedef unsigned int uint;
typedef unsigned char uchar;

#define NB_MAX 256      // max buckets
#define NPB_MAX 2048    // max nodes per bucket

#if defined(__has_builtin)
#if __has_builtin(__builtin_amdgcn_cvt_pk_f32_fp8) && __has_builtin(__builtin_amdgcn_cvt_pk_fp8_f32)
#define HW_FP8 1
#endif
#endif

typedef __attribute__((ext_vector_type(2))) float v2f;

// ---------------- fp8 e4m3 codecs (internal z/h storage) ----------------
static __device__ __forceinline__ uint f2fp8_sw(float v) {
    v = fminf(fmaxf(v, -448.f), 448.f);
    uint u = __float_as_uint(v);
    uint s = (u >> 24) & 0x80u;
    uint mag = u & 0x7FFFFFFFu;
    uint r = mag + 0x7FFFFu + ((mag >> 20) & 1u);     // RNE to 3 mantissa bits
    if (r < 0x3C800000u) return s;                    // below 2^-6 -> ±0
    uint e8 = (r - 0x3C000000u) >> 20;
    return s | min(e8, 0x7Eu);
}
static __device__ __forceinline__ float fp82f(uint b) {
    uint mag = b & 0x7Fu;
    uint bits = ((b & 0x80u) << 24) | ((mag << 20) + 0x3C000000u);
    return mag ? __uint_as_float(bits) : 0.f;
}
static __device__ __forceinline__ void dec8(uint2 v, float* o) {
#ifdef HW_FP8
    v2f a = __builtin_amdgcn_cvt_pk_f32_fp8((int)v.x, false);
    v2f b = __builtin_amdgcn_cvt_pk_f32_fp8((int)v.x, true);
    v2f c = __builtin_amdgcn_cvt_pk_f32_fp8((int)v.y, false);
    v2f d = __builtin_amdgcn_cvt_pk_f32_fp8((int)v.y, true);
    o[0]=a.x; o[1]=a.y; o[2]=b.x; o[3]=b.y;
    o[4]=c.x; o[5]=c.y; o[6]=d.x; o[7]=d.y;
#else
    o[0]=fp82f(v.x&0xFF); o[1]=fp82f((v.x>>8)&0xFF); o[2]=fp82f((v.x>>16)&0xFF); o[3]=fp82f(v.x>>24);
    o[4]=fp82f(v.y&0xFF); o[5]=fp82f((v.y>>8)&0xFF); o[6]=fp82f((v.y>>16)&0xFF); o[7]=fp82f(v.y>>24);
#endif
}
static __device__ __forceinline__ uint2 enc8(const float* o) {
#ifdef HW_FP8
    int rx = __builtin_amdgcn_cvt_pk_fp8_f32(o[0], o[1], 0, false);
    rx = __builtin_amdgcn_cvt_pk_fp8_f32(o[2], o[3], rx, true);
    int ry = __builtin_amdgcn_cvt_pk_fp8_f32(o[4], o[5], 0, false);
    ry = __builtin_amdgcn_cvt_pk_fp8_f32(o[6], o[7], ry, true);
    return make_uint2((uint)rx, (uint)ry);
#else
    uint2 r;
    r.x = f2fp8_sw(o[0]) | (f2fp8_sw(o[1])<<8) | (f2fp8_sw(o[2])<<16) | (f2fp8_sw(o[3])<<24);
    r.y = f2fp8_sw(o[4]) | (f2fp8_sw(o[5])<<8) | (f2fp8_sw(o[6])<<16) | (f2fp8_sw(o[7])<<24);
    return r;
#endif
}
static __device__ __forceinline__ void dec32(const uchar* row, float* o) {
    const uint4* r4 = (const uint4*)row;
    uint4 A = r4[0], B = r4[1];
    dec8(make_uint2(A.x,A.y), o); dec8(make_uint2(A.z,A.w), o+8);
    dec8(make_uint2(B.x,B.y), o+16); dec8(make_uint2(B.z,B.w), o+24);
}

// ---------------- wave-level inclusive scan (64 lanes) ----------------
static __device__ __forceinline__ unsigned wave_incl_scan(unsigned v) {
    int lane = threadIdx.x & 63;
    #pragma unroll
    for (int d = 1; d < 64; d <<= 1) {
        unsigned t = (unsigned)__shfl_up((int)v, d, 64);
        if (lane >= d) v += t;
    }
    return v;
}

// exclusive block scan: in[0..n) -> out[0..n), n <= 2048, 256 threads, wscr = shared[4]
static __device__ void block_excl_scan(const uint* in, uint* out, int n, uint* wscr) {
    int tid = threadIdx.x;
    int lane = tid & 63, wid = tid >> 6;
    int base = tid * 8;
    uint v[8], pre[8], s = 0;
    #pragma unroll
    for (int k = 0; k < 8; k++) v[k] = (base + k < n) ? in[base + k] : 0u;
    #pragma unroll
    for (int k = 0; k < 8; k++) { pre[k] = s; s += v[k]; }
    uint is = wave_incl_scan(s);
    __syncthreads();
    if (lane == 63) wscr[wid] = is;
    __syncthreads();
    uint woff = 0;
    for (int wI = 0; wI < wid; wI++) woff += wscr[wI];
    uint excl = is - s + woff;
    #pragma unroll
    for (int k = 0; k < 8; k++) if (base + k < n) out[base + k] = excl + pre[k];
    __syncthreads();
}

// ---------------- phase 1: per-bucket edge & candidate histograms ----------------
__global__ __launch_bounds__(256) void bucket_hist_kernel(const int* src, const int* dst,
                                                          const int* nt, uint* bcnt, uint* bcand,
                                                          int E, int N, int NB, int shift) {
    __shared__ uint bh[NB_MAX], ch[NB_MAX];
    int tid = threadIdx.x;
    bh[tid] = 0; ch[tid] = 0;
    __syncthreads();
    int gs = gridDim.x * 256;
    for (int i = blockIdx.x * 256 + tid; i < E; i += gs) {
        int d = dst[i], s = src[i];
        if ((uint)d < (uint)N && (uint)s < (uint)N) atomicAdd(&bh[d >> shift], 1u);
    }
    for (int i = blockIdx.x * 256 + tid; i < N; i += gs) {
        if (nt[i] == 0) atomicAdd(&ch[i >> shift], 1u);
    }
    __syncthreads();
    if (bh[tid]) atomicAdd(&bcnt[tid], bh[tid]);
    if (ch[tid]) atomicAdd(&bcand[tid], ch[tid]);
}

// ---------------- phase 2: partition edges into bucket-contiguous packed staging ----------------
// staging entry: (dst_local << 17) | src   (requires N < 2^17, shift <= 15)
__global__ __launch_bounds__(256) void partition_kernel(const int* src, const int* dst,
                                                        const uint* bcnt, uint* alloc0,
                                                        uint* staging, int E, int N, int shift) {
    __shared__ uint bbase_s[NB_MAX];
    __shared__ uint lh[NB_MAX], gb[NB_MAX];
    __shared__ uint ws4[4];
    int tid = threadIdx.x;
    int lane = tid & 63, wid = tid >> 6;
    uint a = bcnt[tid];
    uint ia = wave_incl_scan(a);
    if (lane == 63) ws4[wid] = ia;
    __syncthreads();
    uint off = 0;
    for (int wI = 0; wI < wid; wI++) off += ws4[wI];
    bbase_s[tid] = ia - a + off;
    lh[tid] = 0;
    __syncthreads();
    int base = blockIdx.x * 2048;
    uint mask = (1u << shift) - 1u;
    int breg[8];
    uint rreg[8], pk8[8];
    #pragma unroll
    for (int k = 0; k < 8; k++) {
        int e = base + k * 256 + tid;
        breg[k] = -1;
        if (e < E) {
            int s = src[e], d = dst[e];
            if ((uint)d < (uint)N && (uint)s < (uint)N) {
                int b = d >> shift;
                pk8[k] = (((uint)d & mask) << 17) | (uint)s;
                breg[k] = b;
                rreg[k] = atomicAdd(&lh[b], 1u);
            }
        }
    }
    __syncthreads();
    gb[tid] = lh[tid] ? (bbase_s[tid] + atomicAdd(&alloc0[tid], lh[tid])) : 0u;
    __syncthreads();
    #pragma unroll
    for (int k = 0; k < 8; k++) {
        if (breg[k] >= 0)
            staging[gb[breg[k]] + rreg[k]] = pk8[k];
    }
}

// ---------------- phase 3: per-bucket counting sort + csr_off/dinv/cand_pos + xs rows ----------------
// xs row = (x*dinv, dinv) so layer-1 agg also produces S = dinv_i + sum dinv_j in lane c4==3
__global__ __launch_bounds__(256) void local_csr_kernel(const uint* staging, const uint* bcnt,
                                                        const uint* bcand, const int* nt,
                                                        const float* x,
                                                        int* csr_src, uint* csr_off, uint* cand_pos,
                                                        float* dinv, float4* xs,
                                                        int N, int shift, int NB) {
    __shared__ uint deg[NPB_MAX];
    __shared__ uint ofs[NPB_MAX];
    __shared__ uint ws4[4];
    __shared__ uint sb[4];        // ebase, eend, cb
    int b = blockIdx.x, tid = threadIdx.x;
    int lane = tid & 63, wid = tid >> 6;
    uint a = bcnt[tid];
    uint ia = wave_incl_scan(a);
    if (lane == 63) ws4[wid] = ia;
    __syncthreads();
    uint off = 0;
    for (int wI = 0; wI < wid; wI++) off += ws4[wI];
    if (tid == b) { sb[0] = ia - a + off; sb[1] = ia + off; }
    __syncthreads();
    uint c = bcand[tid];
    uint ic = wave_incl_scan(c);
    if (lane == 63) ws4[wid] = ic;
    __syncthreads();
    uint offc = 0;
    for (int wI = 0; wI < wid; wI++) offc += ws4[wI];
    if (tid == b) sb[2] = ic - c + offc;
    __syncthreads();
    uint ebase = sb[0], eend = sb[1], cb = sb[2];
    int nbase = b << shift;
    int ncount = min(1 << shift, N - nbase);
    for (int i = tid; i < ncount; i += 256) deg[i] = 0;
    __syncthreads();
    for (uint p = ebase + tid; p < eend; p += 256)
        atomicAdd(&deg[staging[p] >> 17], 1u);
    __syncthreads();
    block_excl_scan(deg, ofs, ncount, ws4);
    for (int i = tid; i < ncount; i += 256)
        csr_off[nbase + i] = ebase + ofs[i];
    if (b == NB - 1 && tid == 0) csr_off[N] = eend;
    // fused dinv + xs = (x * dinv, dinv)  (deg still intact)
    for (int i = tid; i < ncount; i += 256) {
        int g = nbase + i;
        float di = rsqrtf((float)(deg[i] + 1u));   // +1 self loop
        dinv[g] = di;
        xs[g] = make_float4(x[3*g] * di, x[3*g+1] * di, x[3*g+2] * di, di);
    }
    __syncthreads();
    for (int i = tid; i < ncount; i += 256) deg[i] = 0;   // reuse as running counters
    __syncthreads();
    for (uint p = ebase + tid; p < eend; p += 256) {
        uint pkv = staging[p];
        uint dl = pkv >> 17;
        uint pos = ebase + ofs[dl] + atomicAdd(&deg[dl], 1u);
        csr_src[pos] = (int)(pkv & 0x1FFFFu);
    }
    __syncthreads();
    for (int i = tid; i < ncount; i += 256) deg[i] = (nt[nbase + i] == 0) ? 1u : 0u;
    __syncthreads();
    block_excl_scan(deg, ofs, ncount, ws4);
    for (int i = tid; i < ncount; i += 256) cand_pos[nbase + i] = cb + ofs[i];
}

// ---------------- layer-1 aggregate: rank-3 trick, block-level work-stealing chunks ----------------
// Writes hb = fp8(dinv_i * h1_i) (pre-scaled for next layer's linear aggregation),
// Sbuf[i] = dinv_i + sum_j dinv_j (from xs.w channel), stats over RAW h1.
__global__ __launch_bounds__(256) void agg1_kernel(const float* xs, const int* csr_src,
                                                   const uint* csr_off, const float* dinv,
                                                   const float* W1, const float* b1, uchar* hb,
                                                   float* Sbuf, int n,
                                                   float* stats_sum, float* stats_sq,
                                                   uint* gt) {
    const int tid = threadIdx.x;
    const int wave = tid >> 6;
    const int lane = tid & 63;
    const int c4 = lane & 3;
    const int slot = lane >> 2;
    const int qlead = lane & ~3;
    __shared__ float W1s[96];
    __shared__ uint s_lt, s_chunk;
    if (tid < 96) W1s[tid] = W1[tid];
    float bv[8];
    #pragma unroll
    for (int j = 0; j < 8; j++) bv[j] = b1[c4 * 8 + j];
    float bs[8], bq[8];
    #pragma unroll
    for (int j = 0; j < 8; j++) { bs[j] = 0.f; bq[j] = 0.f; }
    __syncthreads();
    while (true) {
        if (tid == 0) s_chunk = atomicAdd(gt, 1u);
        __syncthreads();
        uint cbase = s_chunk * 128u;
        if (cbase >= (uint)n) break;
        uint avail = min((uint)n - cbase, 128u);
        if (tid == 0) s_lt = 0u;
        __syncthreads();
        while (true) {
            uint li = 0;
            if (c4 == 0) li = atomicAdd(&s_lt, 1u);
            li = (uint)__shfl((int)li, qlead, 64);
            if (li >= avail) break;
            uint node = cbase + li;
            uint s = csr_off[node], e = csr_off[node + 1];
            float acc = xs[(size_t)node * 4 + c4];     // self loop (xs has dinv folded; .w = dinv)
            for (uint p = s; p < e; p += 8) {
                uint idx[8];
                float wg[8];
                #pragma unroll
                for (int j = 0; j < 8; j++) {
                    uint q = p + (uint)j;
                    uint qc = min(q, e - 1u);
                    idx[j] = (uint)csr_src[qc];
                    wg[j] = (q < e) ? 1.f : 0.f;
                }
                #pragma unroll
                for (int j = 0; j < 8; j++)
                    acc = fmaf(wg[j], xs[(size_t)idx[j] * 4 + c4], acc);
            }
            if (c4 == 3) Sbuf[node] = acc;             // S_i (raw sum of dinv over closed nbhd)
            float di = dinv[node];
            float u = di * acc;
            float u0 = __shfl(u, qlead, 64);
            float u1 = __shfl(u, qlead + 1, 64);
            float u2 = __shfl(u, qlead + 2, 64);
            float hv[8], sv[8];
            #pragma unroll
            for (int j = 0; j < 8; j++) {
                int ch = c4 * 8 + j;
                float o = u0 * W1s[ch] + u1 * W1s[32 + ch] + u2 * W1s[64 + ch] + bv[j];
                hv[j] = fmaxf(o, 0.f);
                sv[j] = di * hv[j];                    // pre-scaled storage
            }
            *(uint2*)(hb + (size_t)node * 32 + c4 * 8) = enc8(sv);
            #pragma unroll
            for (int j = 0; j < 8; j++) { bs[j] += hv[j]; bq[j] += hv[j] * hv[j]; }
        }
        __syncthreads();
    }
    #pragma unroll
    for (int m = 4; m < 64; m <<= 1) {
        #pragma unroll
        for (int j = 0; j < 8; j++) {
            bs[j] += __shfl_xor(bs[j], m, 64);
            bq[j] += __shfl_xor(bq[j], m, 64);
        }
    }
    __shared__ float ssum[4][32], ssq[4][32];
    if (slot == 0) {
        #pragma unroll
        for (int j = 0; j < 8; j++) { ssum[wave][c4 * 8 + j] = bs[j]; ssq[wave][c4 * 8 + j] = bq[j]; }
    }
    __syncthreads();
    if (tid < 32) {
        atomicAdd(&stats_sum[tid], ssum[0][tid] + ssum[1][tid] + ssum[2][tid] + ssum[3][tid]);
        atomicAdd(&stats_sq[tid],  ssq[0][tid] + ssq[1][tid] + ssq[2][tid] + ssq[3][tid]);
    }
}

// ---------------- fused aggregate + BN-fold + W transform (layers 2/3) ----------------
// Input hin rows are fp8(dinv_m * h_m). Aggregate H_i = sum over closed nbhd (plain sum),
// then out = relu(dinv_i * (W^T(a o H_i) + cs*S_i) + bias).
// MODE 0: store pre-scaled fp8(dinv_i*out) + BN stats of raw out (layer 2).
// MODE 1: store RAW fp8(out) + rowsum/maxkey (layer 3, consumed by head).
template<int MODE>
__global__ __launch_bounds__(256) void aggbn_kernel(const uchar* hin, const int* csr_src,
                                                    const uint* csr_off, const float* dinv,
                                                    const float* Sbuf,
                                                    const float* stats_sum, const float* stats_sq,
                                                    const float* g, const float* be,
                                                    const float* W, const float* bias,
                                                    uchar* hout, int n, float inv_n,
                                                    float* osum, float* osq,
                                                    float* rowsum, uint* maxkey, uint* gt) {
    const int tid = threadIdx.x;
    const int wave = tid >> 6;
    const int lane = tid & 63;
    const int c4 = lane & 3;
    const int slot = lane >> 2;
    const int qlead = lane & ~3;
    __shared__ float Ws[1024];
    __shared__ float cs[32], a_s[32], d_s[32];
    __shared__ uint s_lt, s_chunk;
    if (tid < 32) {
        float mu = stats_sum[tid] * inv_n;
        float var = fmaxf(stats_sq[tid] * inv_n - mu * mu, 0.f);
        float a = g[tid] * rsqrtf(var + 1e-5f);
        a_s[tid] = a;
        d_s[tid] = be[tid] - mu * a;
    }
    __syncthreads();
    for (int t = tid; t < 1024; t += 256) Ws[t] = a_s[t >> 5] * W[t];
    if (tid < 32) {
        float c = 0.f;
        for (int k = 0; k < 32; k++) c += d_s[k] * W[k * 32 + tid];
        cs[tid] = c;
    }
    float bv[8];
    #pragma unroll
    for (int j = 0; j < 8; j++) bv[j] = bias[c4 * 8 + j];
    float bs[8], bq[8];
    if (MODE == 0) {
        #pragma unroll
        for (int j = 0; j < 8; j++) { bs[j] = 0.f; bq[j] = 0.f; }
    }
    float lmax = -3.0e38f;
    __syncthreads();
    while (true) {
        if (tid == 0) s_chunk = atomicAdd(gt, 1u);
        __syncthreads();
        uint cbase = s_chunk * 128u;
        if (cbase >= (uint)n) break;
        uint avail = min((uint)n - cbase, 128u);
        if (tid == 0) s_lt = 0u;
        __syncthreads();
        while (true) {
            uint li = 0;
            if (c4 == 0) li = atomicAdd(&s_lt, 1u);
            li = (uint)__shfl((int)li, qlead, 64);
            if (li >= avail) break;
            uint node = cbase + li;
            uint s = csr_off[node], e = csr_off[node + 1];
            float acc[8];
            dec8(*(const uint2*)(hin + (size_t)node * 32 + c4 * 8), acc);   // self (pre-scaled)
            for (uint p = s; p < e; p += 8) {
                uint idx[8];
                float wg[8];
                #pragma unroll
                for (int j = 0; j < 8; j++) {
                    uint q = p + (uint)j;
                    uint qc = min(q, e - 1u);
                    idx[j] = (uint)csr_src[qc];
                    wg[j] = (q < e) ? 1.f : 0.f;
                }
                #pragma unroll
                for (int j = 0; j < 8; j++) {
                    float t[8];
                    dec8(*(const uint2*)(hin + (size_t)idx[j] * 32 + c4 * 8), t);
                    #pragma unroll
                    for (int cI = 0; cI < 8; cI++) acc[cI] = fmaf(wg[j], t[cI], acc[cI]);
                }
            }
            // gather full 32-channel H_i across the quad (32 shuffles)
            float af[32];
            #pragma unroll
            for (int cc = 0; cc < 4; cc++) {
                #pragma unroll
                for (int r = 0; r < 8; r++)
                    af[cc * 8 + r] = __shfl(acc[r], qlead + cc, 64);
            }
            float di = dinv[node];
            float Sv = Sbuf[node];
            float hv[8], sv[8];
            #pragma unroll
            for (int jj = 0; jj < 8; jj++) {
                int j = c4 * 8 + jj;
                float t = cs[j] * Sv;
                #pragma unroll
                for (int k = 0; k < 32; k++) t = fmaf(Ws[k * 32 + j], af[k], t);
                hv[jj] = fmaxf(fmaf(di, t, bv[jj]), 0.f);
            }
            if (MODE == 0) {
                #pragma unroll
                for (int jj = 0; jj < 8; jj++) sv[jj] = di * hv[jj];   // pre-scale for layer 3
                *(uint2*)(hout + (size_t)node * 32 + c4 * 8) = enc8(sv);
                #pragma unroll
                for (int jj = 0; jj < 8; jj++) { bs[jj] += hv[jj]; bq[jj] += hv[jj] * hv[jj]; }
            } else {
                *(uint2*)(hout + (size_t)node * 32 + c4 * 8) = enc8(hv);  // raw h3 for head
                float rs = ((hv[0] + hv[1]) + (hv[2] + hv[3])) + ((hv[4] + hv[5]) + (hv[6] + hv[7]));
                rs += __shfl_xor(rs, 1, 64);
                rs += __shfl_xor(rs, 2, 64);
                if (c4 == 0) { rowsum[node] = rs; lmax = fmaxf(lmax, rs); }
            }
        }
        __syncthreads();
    }
    if (MODE == 0) {
        #pragma unroll
        for (int m = 4; m < 64; m <<= 1) {
            #pragma unroll
            for (int j = 0; j < 8; j++) {
                bs[j] += __shfl_xor(bs[j], m, 64);
                bq[j] += __shfl_xor(bq[j], m, 64);
            }
        }
        __shared__ float ssum[4][32], ssq[4][32];
        if (slot == 0) {
            #pragma unroll
            for (int j = 0; j < 8; j++) { ssum[wave][c4 * 8 + j] = bs[j]; ssq[wave][c4 * 8 + j] = bq[j]; }
        }
        __syncthreads();
        if (tid < 32) {
            atomicAdd(&osum[tid], ssum[0][tid] + ssum[1][tid] + ssum[2][tid] + ssum[3][tid]);
            atomicAdd(&osq[tid],  ssq[0][tid] + ssq[1][tid] + ssq[2][tid] + ssq[3][tid]);
        }
    } else {
        #pragma unroll
        for (int m = 1; m < 64; m <<= 1) lmax = fmaxf(lmax, __shfl_xor(lmax, m, 64));
        __shared__ float lm[4];
        if (lane == 0) lm[wave] = lmax;
        __syncthreads();
        if (tid == 0) {
            float m = fmaxf(fmaxf(lm[0], lm[1]), fmaxf(lm[2], lm[3]));
            uint u = __float_as_uint(m);
            uint key = (u & 0x80000000u) ? ~u : (u | 0x80000000u);
            atomicMax(maxkey, key);
        }
    }
}

// ---------------- fused heads: candidate scores + softmax pooling + graph head ----------------
__global__ __launch_bounds__(256) void head_kernel(const uchar* hb, const int* nt,
                                                   const uint* pos, const float* Wc1,
                                                   const float* bc1, const float* Wc2,
                                                   const float* bc2, const float* rowsum,
                                                   const uint* maxkey, float* gvec, float* Zp,
                                                   uint* ticket, const float* Wd1,
                                                   const float* bd1, const float* Wd2,
                                                   const float* bd2, float* out, int n, int C) {
    __shared__ float W1s[512], b1s[16], W2s[16];
    __shared__ float ls[256];
    __shared__ float ge[32], tt[16];
    __shared__ int lastflag;
    int tid = threadIdx.x;
    for (int t = tid; t < 512; t += 256) W1s[t] = Wc1[t];
    if (tid < 16) { b1s[tid] = bc1[tid]; W2s[tid] = Wc2[tid]; }
    __syncthreads();
    // Part A: candidate scores
    int i = blockIdx.x * 256 + tid;
    if (i < n && nt[i] == 0) {
        float hv[32];
        dec32(hb + (size_t)i * 32, hv);
        float s = bc2[0];
        #pragma unroll
        for (int j = 0; j < 16; j++) {
            float u = b1s[j];
            #pragma unroll
            for (int k = 0; k < 32; k++) u += hv[k] * W1s[k * 16 + j];
            s += fmaxf(u, 0.f) * W2s[j];
        }
        s = fminf(fmaxf(s, -1000.f), 1000.f);
        uint p = pos[i];
        if (p < (uint)C) {
            out[p] = s;
            out[C + 1 + p] = (float)i;
        }
    }
    // Part B: pooling partials (lane reads one fp8 channel)
    uint key = *maxkey;
    float M = 0.f;
    if (key != 0u) M = (key & 0x80000000u) ? __uint_as_float(key ^ 0x80000000u) : __uint_as_float(~key);
    int lane = tid & 31, grp = tid >> 5;
    int stride = gridDim.x * 8;
    float accZ = 0.f, accg = 0.f;
    for (int node = blockIdx.x * 8 + grp; node < n; node += stride) {
        float ew = __expf(rowsum[node] - M);
        accg += fp82f(hb[(size_t)node * 32 + lane]) * ew;
        if (lane == 0) accZ += ew;
    }
    ls[tid] = accg;
    __syncthreads();
    if (tid < 32) {
        float a = 0.f;
        #pragma unroll
        for (int g = 0; g < 8; g++) a += ls[tid + 32 * g];
        atomicAdd(&gvec[tid], a);
    }
    __syncthreads();
    ls[tid] = (lane == 0) ? accZ : 0.f;
    __syncthreads();
    if (tid == 0) {
        float a = 0.f;
        for (int t = 0; t < 256; t += 32) a += ls[t];
        atomicAdd(Zp, a);
        __threadfence();
        uint old = atomicAdd(ticket, 1u);
        lastflag = (old == gridDim.x - 1) ? 1 : 0;
    }
    __syncthreads();
    // Part C: last block computes graph head
    if (lastflag) {
        __threadfence();
        if (tid < 32) ge[tid] = atomicAdd(&gvec[tid], 0.f);
        if (tid == 0) ls[0] = atomicAdd(Zp, 0.f);
        __syncthreads();
        float Zv = fmaxf(ls[0], 1e-30f);
        if (tid < 32) ge[tid] /= Zv;
        __syncthreads();
        if (tid < 16) {
            float s = bd1[tid];
            for (int k = 0; k < 32; k++) s += ge[k] * Wd1[k * 16 + tid];
            tt[tid] = fmaxf(s, 0.f);
        }
        __syncthreads();
        if (tid == 0) {
            float s = bd2[0];
            for (int j = 0; j < 16; j++) s += tt[j] * Wd2[j];
            out[C] = fminf(fmaxf(s, -1000.f), 1000.f);
        }
    }
}

// ---------------- host launch ----------------
extern "C" void kernel_launch(void* const* d_in, const int* in_sizes, int n_in,
                              void* d_out, int out_size, void* d_ws, size_t ws_size,
                              hipStream_t stream) {
    const float* x   = (const float*)d_in[0];
    const int*   ei  = (const int*)d_in[1];
    const int*   nt  = (const int*)d_in[2];
    const float* W1  = (const float*)d_in[3];  const float* b1  = (const float*)d_in[4];
    const float* W2  = (const float*)d_in[5];  const float* b2  = (const float*)d_in[6];
    const float* W3  = (const float*)d_in[7];  const float* b3  = (const float*)d_in[8];
    const float* g1  = (const float*)d_in[9];  const float* be1 = (const float*)d_in[10];
    const float* g2  = (const float*)d_in[11]; const float* be2 = (const float*)d_in[12];
    const float* Wc1 = (const float*)d_in[13]; const float* bc1 = (const float*)d_in[14];
    const float* Wc2 = (const float*)d_in[15]; const float* bc2 = (const float*)d_in[16];
    const float* Wd1 = (const float*)d_in[17]; const float* bd1 = (const float*)d_in[18];
    const float* Wd2 = (const float*)d_in[19]; const float* bd2 = (const float*)d_in[20];

    const int N = in_sizes[0] / 3;
    const int E = in_sizes[1] / 2;
    const int C = (out_size - 1) / 2;
    const int* e_src = ei;
    const int* e_dst = ei + E;
    float* out = (float*)d_out;

    // bucket geometry: nodes/bucket = 1<<shift, NB <= 256 (packing needs N < 2^17)
    int shift = 9;
    while (((N + (1 << shift) - 1) >> shift) > NB_MAX) shift++;
    const int NB = (N + (1 << shift) - 1) >> shift;

    // ---- workspace carve-up (~14 MB) ----
    char* w = (char*)d_ws;
    auto alloc = [&](size_t bytes) { void* p = (void*)w; w += (bytes + 255) & ~(size_t)255; return p; };
    float*    stats  = (float*)alloc(256 * 4);     // zeroed
    uint*     bcnt   = (uint*)alloc(NB_MAX * 4);   // zeroed
    uint*     bcand  = (uint*)alloc(NB_MAX * 4);   // zeroed
    uint*     alloc0 = (uint*)alloc(NB_MAX * 4);   // zeroed
    size_t zero_bytes = (size_t)((char*)w - (char*)stats);
    float*    dinv   = (float*)alloc((size_t)N * 4);
    uint*     csr_off= (uint*)alloc((size_t)(N + 1) * 4);
    uint*     cand_pos=(uint*)alloc((size_t)N * 4);
    float*    rowsum = (float*)alloc((size_t)N * 4);
    float*    Sbuf   = (float*)alloc((size_t)N * 4);
    int*      csr_src= (int*)alloc((size_t)E * 4);
    uint*     staging= (uint*)alloc((size_t)E * 4);
    uchar*    zb     = (uchar*)alloc((size_t)N * 32);
    uchar*    hb     = (uchar*)alloc((size_t)N * 32);
    // xs (N*16B float4) aliases zb (dead until aggbn<0> writes h2 into zb)
    float4*   xs     = (float4*)zb;

    float* sum1 = stats;       float* sq1 = stats + 32;
    float* sum2 = stats + 64;  float* sq2 = stats + 96;
    float* gvec = stats + 128; float* Zp  = stats + 160;
    uint* maxkey = (uint*)(stats + 161);
    uint* ticket = (uint*)(stats + 162);
    uint* gt1 = (uint*)(stats + 163);
    uint* gt2 = (uint*)(stats + 164);
    uint* gt3 = (uint*)(stats + 165);

    hipMemsetAsync(stats, 0, zero_bytes, stream);

    const int gN   = (N + 255) / 256;
    const int gPar = (E + 2047) / 2048;
    int gAgg = (N + 127) / 128;
    if (gAgg > 1024) gAgg = 1024;                  // R4: occupancy lever — was 512 (8 waves/CU), now 782 (~12 waves/CU)
    const float inv_n = 1.0f / (float)N;

    // ---- CSR build (XCD-local two-phase counting sort, packed staging) ----
    hipLaunchKernelGGL(bucket_hist_kernel, dim3(784), dim3(256), 0, stream, e_src, e_dst, nt, bcnt, bcand, E, N, NB, shift);
    hipLaunchKernelGGL(partition_kernel, dim3(gPar), dim3(256), 0, stream, e_src, e_dst, bcnt, alloc0, staging, E, N, shift);
    hipLaunchKernelGGL(local_csr_kernel, dim3(NB), dim3(256), 0, stream, staging, bcnt, bcand, nt,
                       x, csr_src, csr_off, cand_pos, dinv, xs, N, shift, NB);

    // ---- layer 1 (rank-3 aggregation + fused W1; writes pre-scaled h1 + S) ----
    hipLaunchKernelGGL(agg1_kernel, dim3(gAgg), dim3(256), 0, stream, (const float*)xs, csr_src, csr_off,
                       dinv, W1, b1, hb, Sbuf, N, sum1, sq1, gt1);

    // ---- layer 2: aggregate + BN1-fold + W2 (gemm eliminated algebraically) ----
    hipLaunchKernelGGL((aggbn_kernel<0>), dim3(gAgg), dim3(256), 0, stream, hb, csr_src, csr_off,
                       dinv, Sbuf, sum1, sq1, g1, be1, W2, b2, zb, N, inv_n,
                       sum2, sq2, rowsum, maxkey, gt2);

    // ---- layer 3: aggregate + BN2-fold + W3 ----
    hipLaunchKernelGGL((aggbn_kernel<1>), dim3(gAgg), dim3(256), 0, stream, zb, csr_src, csr_off,
                       dinv, Sbuf, sum2, sq2, g2, be2, W3, b3, hb, N, inv_n,
                       sum1, sq1, rowsum, maxkey, gt3);

    // ---- fused heads ----
    hipLaunchKernelGGL(head_kernel, dim3(gN), dim3(256), 0, stream, hb, nt, cand_pos,
                       Wc1, bc1, Wc2, bc2, rowsum, maxkey, gvec, Zp, ticket,
                       Wd1, bd1, Wd2, bd2, out, N, C);
}

// Round 5
// 324.443 us; speedup vs baseline: 1.0681x; 1.0154x over previous
//
#include <hip/hip_runtime.h>

typedef unsigned int uint;
typedef unsigned char uchar;

#define NB_MAX 256      // max buckets
#define NPB_MAX 2048    // max nodes per bucket

#if defined(__has_builtin)
#if __has_builtin(__builtin_amdgcn_cvt_pk_f32_fp8) && __has_builtin(__builtin_amdgcn_cvt_pk_fp8_f32)
#define HW_FP8 1
#endif
#endif

typedef __attribute__((ext_vector_type(2))) float v2f;

// ---------------- fp8 e4m3 codecs (internal z/h storage) ----------------
static __device__ __forceinline__ uint f2fp8_sw(float v) {
    v = fminf(fmaxf(v, -448.f), 448.f);
    uint u = __float_as_uint(v);
    uint s = (u >> 24) & 0x80u;
    uint mag = u & 0x7FFFFFFFu;
    uint r = mag + 0x7FFFFu + ((mag >> 20) & 1u);     // RNE to 3 mantissa bits
    if (r < 0x3C800000u) return s;                    // below 2^-6 -> ±0
    uint e8 = (r - 0x3C000000u) >> 20;
    return s | min(e8, 0x7Eu);
}
static __device__ __forceinline__ float fp82f(uint b) {
    uint mag = b & 0x7Fu;
    uint bits = ((b & 0x80u) << 24) | ((mag << 20) + 0x3C000000u);
    return mag ? __uint_as_float(bits) : 0.f;
}
static __device__ __forceinline__ void dec8(uint2 v, float* o) {
#ifdef HW_FP8
    v2f a = __builtin_amdgcn_cvt_pk_f32_fp8((int)v.x, false);
    v2f b = __builtin_amdgcn_cvt_pk_f32_fp8((int)v.x, true);
    v2f c = __builtin_amdgcn_cvt_pk_f32_fp8((int)v.y, false);
    v2f d = __builtin_amdgcn_cvt_pk_f32_fp8((int)v.y, true);
    o[0]=a.x; o[1]=a.y; o[2]=b.x; o[3]=b.y;
    o[4]=c.x; o[5]=c.y; o[6]=d.x; o[7]=d.y;
#else
    o[0]=fp82f(v.x&0xFF); o[1]=fp82f((v.x>>8)&0xFF); o[2]=fp82f((v.x>>16)&0xFF); o[3]=fp82f(v.x>>24);
    o[4]=fp82f(v.y&0xFF); o[5]=fp82f((v.y>>8)&0xFF); o[6]=fp82f((v.y>>16)&0xFF); o[7]=fp82f(v.y>>24);
#endif
}
static __device__ __forceinline__ uint2 enc8(const float* o) {
#ifdef HW_FP8
    int rx = __builtin_amdgcn_cvt_pk_fp8_f32(o[0], o[1], 0, false);
    rx = __builtin_amdgcn_cvt_pk_fp8_f32(o[2], o[3], rx, true);
    int ry = __builtin_amdgcn_cvt_pk_fp8_f32(o[4], o[5], 0, false);
    ry = __builtin_amdgcn_cvt_pk_fp8_f32(o[6], o[7], ry, true);
    return make_uint2((uint)rx, (uint)ry);
#else
    uint2 r;
    r.x = f2fp8_sw(o[0]) | (f2fp8_sw(o[1])<<8) | (f2fp8_sw(o[2])<<16) | (f2fp8_sw(o[3])<<24);
    r.y = f2fp8_sw(o[4]) | (f2fp8_sw(o[5])<<8) | (f2fp8_sw(o[6])<<16) | (f2fp8_sw(o[7])<<24);
    return r;
#endif
}
static __device__ __forceinline__ void dec16(uint4 v, float* o) {
    dec8(make_uint2(v.x, v.y), o);
    dec8(make_uint2(v.z, v.w), o + 8);
}
static __device__ __forceinline__ void enc16(const float* o, uchar* dst) {
    uint2 a = enc8(o), b = enc8(o + 8);
    *(uint4*)dst = make_uint4(a.x, a.y, b.x, b.y);
}
static __device__ __forceinline__ void dec32(const uchar* row, float* o) {
    const uint4* r4 = (const uint4*)row;
    uint4 A = r4[0], B = r4[1];
    dec8(make_uint2(A.x,A.y), o); dec8(make_uint2(A.z,A.w), o+8);
    dec8(make_uint2(B.x,B.y), o+16); dec8(make_uint2(B.z,B.w), o+24);
}

// ---------------- wave-level inclusive scan (64 lanes) ----------------
static __device__ __forceinline__ unsigned wave_incl_scan(unsigned v) {
    int lane = threadIdx.x & 63;
    #pragma unroll
    for (int d = 1; d < 64; d <<= 1) {
        unsigned t = (unsigned)__shfl_up((int)v, d, 64);
        if (lane >= d) v += t;
    }
    return v;
}

// exclusive block scan: in[0..n) -> out[0..n), n <= 2048, 256 threads, wscr = shared[4]
static __device__ void block_excl_scan(const uint* in, uint* out, int n, uint* wscr) {
    int tid = threadIdx.x;
    int lane = tid & 63, wid = tid >> 6;
    int base = tid * 8;
    uint v[8], pre[8], s = 0;
    #pragma unroll
    for (int k = 0; k < 8; k++) v[k] = (base + k < n) ? in[base + k] : 0u;
    #pragma unroll
    for (int k = 0; k < 8; k++) { pre[k] = s; s += v[k]; }
    uint is = wave_incl_scan(s);
    __syncthreads();
    if (lane == 63) wscr[wid] = is;
    __syncthreads();
    uint woff = 0;
    for (int wI = 0; wI < wid; wI++) woff += wscr[wI];
    uint excl = is - s + woff;
    #pragma unroll
    for (int k = 0; k < 8; k++) if (base + k < n) out[base + k] = excl + pre[k];
    __syncthreads();
}

// ---------------- phase 1: per-bucket edge & candidate histograms ----------------
__global__ __launch_bounds__(256) void bucket_hist_kernel(const int* src, const int* dst,
                                                          const int* nt, uint* bcnt, uint* bcand,
                                                          int E, int N, int NB, int shift) {
    __shared__ uint bh[NB_MAX], ch[NB_MAX];
    int tid = threadIdx.x;
    bh[tid] = 0; ch[tid] = 0;
    __syncthreads();
    int gs = gridDim.x * 256;
    for (int i = blockIdx.x * 256 + tid; i < E; i += gs) {
        int d = dst[i], s = src[i];
        if ((uint)d < (uint)N && (uint)s < (uint)N) atomicAdd(&bh[d >> shift], 1u);
    }
    for (int i = blockIdx.x * 256 + tid; i < N; i += gs) {
        if (nt[i] == 0) atomicAdd(&ch[i >> shift], 1u);
    }
    __syncthreads();
    if (bh[tid]) atomicAdd(&bcnt[tid], bh[tid]);
    if (ch[tid]) atomicAdd(&bcand[tid], ch[tid]);
}

// ---------------- phase 2: partition edges into bucket-contiguous packed staging ----------------
// staging entry: (dst_local << 17) | src   (requires N < 2^17, shift <= 15)
__global__ __launch_bounds__(256) void partition_kernel(const int* src, const int* dst,
                                                        const uint* bcnt, uint* alloc0,
                                                        uint* staging, int E, int N, int shift) {
    __shared__ uint bbase_s[NB_MAX];
    __shared__ uint lh[NB_MAX], gb[NB_MAX];
    __shared__ uint ws4[4];
    int tid = threadIdx.x;
    int lane = tid & 63, wid = tid >> 6;
    uint a = bcnt[tid];
    uint ia = wave_incl_scan(a);
    if (lane == 63) ws4[wid] = ia;
    __syncthreads();
    uint off = 0;
    for (int wI = 0; wI < wid; wI++) off += ws4[wI];
    bbase_s[tid] = ia - a + off;
    lh[tid] = 0;
    __syncthreads();
    int base = blockIdx.x * 2048;
    uint mask = (1u << shift) - 1u;
    int breg[8];
    uint rreg[8], pk8[8];
    #pragma unroll
    for (int k = 0; k < 8; k++) {
        int e = base + k * 256 + tid;
        breg[k] = -1;
        if (e < E) {
            int s = src[e], d = dst[e];
            if ((uint)d < (uint)N && (uint)s < (uint)N) {
                int b = d >> shift;
                pk8[k] = (((uint)d & mask) << 17) | (uint)s;
                breg[k] = b;
                rreg[k] = atomicAdd(&lh[b], 1u);
            }
        }
    }
    __syncthreads();
    gb[tid] = lh[tid] ? (bbase_s[tid] + atomicAdd(&alloc0[tid], lh[tid])) : 0u;
    __syncthreads();
    #pragma unroll
    for (int k = 0; k < 8; k++) {
        if (breg[k] >= 0)
            staging[gb[breg[k]] + rreg[k]] = pk8[k];
    }
}

// ---------------- phase 3: per-bucket counting sort + csr_off/dinv/cand_pos + xs rows ----------------
// xs row = (x*dinv, dinv) so layer-1 agg also produces S = dinv_i + sum dinv_j
__global__ __launch_bounds__(256) void local_csr_kernel(const uint* staging, const uint* bcnt,
                                                        const uint* bcand, const int* nt,
                                                        const float* x,
                                                        int* csr_src, uint* csr_off, uint* cand_pos,
                                                        float* dinv, float4* xs,
                                                        int N, int shift, int NB) {
    __shared__ uint deg[NPB_MAX];
    __shared__ uint ofs[NPB_MAX];
    __shared__ uint ws4[4];
    __shared__ uint sb[4];        // ebase, eend, cb
    int b = blockIdx.x, tid = threadIdx.x;
    int lane = tid & 63, wid = tid >> 6;
    uint a = bcnt[tid];
    uint ia = wave_incl_scan(a);
    if (lane == 63) ws4[wid] = ia;
    __syncthreads();
    uint off = 0;
    for (int wI = 0; wI < wid; wI++) off += ws4[wI];
    if (tid == b) { sb[0] = ia - a + off; sb[1] = ia + off; }
    __syncthreads();
    uint c = bcand[tid];
    uint ic = wave_incl_scan(c);
    if (lane == 63) ws4[wid] = ic;
    __syncthreads();
    uint offc = 0;
    for (int wI = 0; wI < wid; wI++) offc += ws4[wI];
    if (tid == b) sb[2] = ic - c + offc;
    __syncthreads();
    uint ebase = sb[0], eend = sb[1], cb = sb[2];
    int nbase = b << shift;
    int ncount = min(1 << shift, N - nbase);
    for (int i = tid; i < ncount; i += 256) deg[i] = 0;
    __syncthreads();
    for (uint p = ebase + tid; p < eend; p += 256)
        atomicAdd(&deg[staging[p] >> 17], 1u);
    __syncthreads();
    block_excl_scan(deg, ofs, ncount, ws4);
    for (int i = tid; i < ncount; i += 256)
        csr_off[nbase + i] = ebase + ofs[i];
    if (b == NB - 1 && tid == 0) csr_off[N] = eend;
    // fused dinv + xs = (x * dinv, dinv)  (deg still intact)
    for (int i = tid; i < ncount; i += 256) {
        int g = nbase + i;
        float di = rsqrtf((float)(deg[i] + 1u));   // +1 self loop
        dinv[g] = di;
        xs[g] = make_float4(x[3*g] * di, x[3*g+1] * di, x[3*g+2] * di, di);
    }
    __syncthreads();
    for (int i = tid; i < ncount; i += 256) deg[i] = 0;   // reuse as running counters
    __syncthreads();
    for (uint p = ebase + tid; p < eend; p += 256) {
        uint pkv = staging[p];
        uint dl = pkv >> 17;
        uint pos = ebase + ofs[dl] + atomicAdd(&deg[dl], 1u);
        csr_src[pos] = (int)(pkv & 0x1FFFFu);
    }
    __syncthreads();
    for (int i = tid; i < ncount; i += 256) deg[i] = (nt[nbase + i] == 0) ? 1u : 0u;
    __syncthreads();
    block_excl_scan(deg, ofs, ncount, ws4);
    for (int i = tid; i < ncount; i += 256) cand_pos[nbase + i] = cb + ofs[i];
}

// ---------------- layer-1 aggregate: PAIR-per-node (2 lanes x float2 = 2 txn/edge) ----------------
// Writes hb = fp8(dinv_i * h1_i) (pre-scaled), Sbuf[i] = closed-nbhd dinv sum, stats over RAW h1.
__global__ __launch_bounds__(256, 2) void agg1_kernel(const float* xs, const int* csr_src,
                                                      const uint* csr_off, const float* dinv,
                                                      const float* W1, const float* b1, uchar* hb,
                                                      float* Sbuf, int n,
                                                      float* stats_sum, float* stats_sq,
                                                      uint* gt) {
    const int tid = threadIdx.x;
    const int wave = tid >> 6;
    const int lane = tid & 63;
    const int c2 = lane & 1;           // pair member: owns channels [c2*16, c2*16+16)
    const int plead = lane & ~1;
    __shared__ float W1s[96];
    __shared__ uint s_lt, s_chunk;
    if (tid < 96) W1s[tid] = W1[tid];
    const float2* xs2 = (const float2*)xs;   // row = 2 float2: {x0*di,x1*di}, {x2*di,di}
    float bv[16];
    #pragma unroll
    for (int j = 0; j < 16; j++) bv[j] = b1[c2 * 16 + j];
    float bs[16], bq[16];
    #pragma unroll
    for (int j = 0; j < 16; j++) { bs[j] = 0.f; bq[j] = 0.f; }
    __syncthreads();
    while (true) {
        if (tid == 0) s_chunk = atomicAdd(gt, 1u);
        __syncthreads();
        uint cbase = s_chunk * 128u;
        if (cbase >= (uint)n) break;
        uint avail = min((uint)n - cbase, 128u);
        if (tid == 0) s_lt = 0u;
        __syncthreads();
        while (true) {
            uint li = 0;
            if (c2 == 0) li = atomicAdd(&s_lt, 1u);
            li = (uint)__shfl((int)li, plead, 64);
            if (li >= avail) break;
            uint node = cbase + li;
            uint s = csr_off[node], e = csr_off[node + 1];
            float2 selfv = xs2[(size_t)node * 2 + c2];
            float a0 = selfv.x, a1 = selfv.y;            // self loop (dinv folded)
            for (uint p = s; p < e; p += 8) {
                uint idx[8];
                float wg[8];
                #pragma unroll
                for (int j = 0; j < 8; j++) {
                    uint q = p + (uint)j;
                    uint qc = min(q, e - 1u);
                    idx[j] = (uint)csr_src[qc];
                    wg[j] = (q < e) ? 1.f : 0.f;
                }
                #pragma unroll
                for (int j = 0; j < 8; j++) {
                    float2 t = xs2[(size_t)idx[j] * 2 + c2];
                    a0 = fmaf(wg[j], t.x, a0);
                    a1 = fmaf(wg[j], t.y, a1);
                }
            }
            if (c2 == 1) Sbuf[node] = a1;                // S_i (sum of dinv over closed nbhd)
            float di = dinv[node];
            float u0l = di * a0, u1l = di * a1;
            float u0 = __shfl(u0l, plead, 64);           // di * sum(x0*di)
            float u1 = __shfl(u1l, plead, 64);           // di * sum(x1*di)
            float u2 = __shfl(u0l, plead + 1, 64);       // di * sum(x2*di)
            float hv[16], sv[16];
            #pragma unroll
            for (int j = 0; j < 16; j++) {
                int ch = c2 * 16 + j;
                float o = u0 * W1s[ch] + u1 * W1s[32 + ch] + u2 * W1s[64 + ch] + bv[j];
                hv[j] = fmaxf(o, 0.f);
                sv[j] = di * hv[j];                      // pre-scaled storage
            }
            enc16(sv, hb + (size_t)node * 32 + c2 * 16);
            #pragma unroll
            for (int j = 0; j < 16; j++) { bs[j] += hv[j]; bq[j] += hv[j] * hv[j]; }
        }
        __syncthreads();
    }
    #pragma unroll
    for (int m = 2; m < 64; m <<= 1) {
        #pragma unroll
        for (int j = 0; j < 16; j++) {
            bs[j] += __shfl_xor(bs[j], m, 64);
            bq[j] += __shfl_xor(bq[j], m, 64);
        }
    }
    __shared__ float ssum[4][32], ssq[4][32];
    if ((lane >> 1) == 0) {            // lanes 0 (ch 0-15) and 1 (ch 16-31)
        #pragma unroll
        for (int j = 0; j < 16; j++) { ssum[wave][c2 * 16 + j] = bs[j]; ssq[wave][c2 * 16 + j] = bq[j]; }
    }
    __syncthreads();
    if (tid < 32) {
        atomicAdd(&stats_sum[tid], ssum[0][tid] + ssum[1][tid] + ssum[2][tid] + ssum[3][tid]);
        atomicAdd(&stats_sq[tid],  ssq[0][tid] + ssq[1][tid] + ssq[2][tid] + ssq[3][tid]);
    }
}

// ---------------- fused aggregate + BN-fold + W transform (layers 2/3), PAIR-per-node ----------------
// 2 lanes x uint4 (16B) gather = 2 txn/edge (was 4 x 8B). Lane owns 16 channels.
// MODE 0: store pre-scaled fp8(dinv_i*out) + BN stats of raw out (layer 2).
// MODE 1: store RAW fp8(out) + rowsum/maxkey (layer 3, consumed by head).
template<int MODE>
__global__ __launch_bounds__(256, 2) void aggbn_kernel(const uchar* hin, const int* csr_src,
                                                       const uint* csr_off, const float* dinv,
                                                       const float* Sbuf,
                                                       const float* stats_sum, const float* stats_sq,
                                                       const float* g, const float* be,
                                                       const float* W, const float* bias,
                                                       uchar* hout, int n, float inv_n,
                                                       float* osum, float* osq,
                                                       float* rowsum, uint* maxkey, uint* gt) {
    const int tid = threadIdx.x;
    const int wave = tid >> 6;
    const int lane = tid & 63;
    const int c2 = lane & 1;           // pair member: owns channels [c2*16, c2*16+16)
    const int plead = lane & ~1;
    __shared__ float Ws[1024];
    __shared__ float cs[32], a_s[32], d_s[32];
    __shared__ uint s_lt, s_chunk;
    if (tid < 32) {
        float mu = stats_sum[tid] * inv_n;
        float var = fmaxf(stats_sq[tid] * inv_n - mu * mu, 0.f);
        float a = g[tid] * rsqrtf(var + 1e-5f);
        a_s[tid] = a;
        d_s[tid] = be[tid] - mu * a;
    }
    __syncthreads();
    for (int t = tid; t < 1024; t += 256) Ws[t] = a_s[t >> 5] * W[t];
    if (tid < 32) {
        float c = 0.f;
        for (int k = 0; k < 32; k++) c += d_s[k] * W[k * 32 + tid];
        cs[tid] = c;
    }
    float bv[16];
    #pragma unroll
    for (int j = 0; j < 16; j++) bv[j] = bias[c2 * 16 + j];
    float bs[16], bq[16];
    if (MODE == 0) {
        #pragma unroll
        for (int j = 0; j < 16; j++) { bs[j] = 0.f; bq[j] = 0.f; }
    }
    float lmax = -3.0e38f;
    __syncthreads();
    while (true) {
        if (tid == 0) s_chunk = atomicAdd(gt, 1u);
        __syncthreads();
        uint cbase = s_chunk * 128u;
        if (cbase >= (uint)n) break;
        uint avail = min((uint)n - cbase, 128u);
        if (tid == 0) s_lt = 0u;
        __syncthreads();
        while (true) {
            uint li = 0;
            if (c2 == 0) li = atomicAdd(&s_lt, 1u);
            li = (uint)__shfl((int)li, plead, 64);
            if (li >= avail) break;
            uint node = cbase + li;
            uint s = csr_off[node], e = csr_off[node + 1];
            float acc[16];
            dec16(*(const uint4*)(hin + (size_t)node * 32 + c2 * 16), acc);   // self (pre-scaled)
            for (uint p = s; p < e; p += 8) {
                uint idx[8];
                float wg[8];
                #pragma unroll
                for (int j = 0; j < 8; j++) {
                    uint q = p + (uint)j;
                    uint qc = min(q, e - 1u);
                    idx[j] = (uint)csr_src[qc];
                    wg[j] = (q < e) ? 1.f : 0.f;
                }
                #pragma unroll
                for (int j = 0; j < 8; j++) {
                    float t[16];
                    dec16(*(const uint4*)(hin + (size_t)idx[j] * 32 + c2 * 16), t);
                    #pragma unroll
                    for (int cI = 0; cI < 16; cI++) acc[cI] = fmaf(wg[j], t[cI], acc[cI]);
                }
            }
            // partner half of H_i via 16 shuffles (static reg indexing; halves selected via LDS addr)
            float pacc[16];
            #pragma unroll
            for (int r = 0; r < 16; r++) pacc[r] = __shfl_xor(acc[r], 1, 64);
            float di = dinv[node];
            float Sv = Sbuf[node];
            const int ownk = c2 * 16, prtk = 16 - c2 * 16;
            float hv[16];
            #pragma unroll
            for (int jj = 0; jj < 16; jj++) {
                int j = c2 * 16 + jj;
                float t = cs[j] * Sv;
                #pragma unroll
                for (int r = 0; r < 16; r++) t = fmaf(Ws[(ownk + r) * 32 + j], acc[r], t);
                #pragma unroll
                for (int r = 0; r < 16; r++) t = fmaf(Ws[(prtk + r) * 32 + j], pacc[r], t);
                hv[jj] = fmaxf(fmaf(di, t, bv[jj]), 0.f);
            }
            if (MODE == 0) {
                float sv[16];
                #pragma unroll
                for (int jj = 0; jj < 16; jj++) sv[jj] = di * hv[jj];   // pre-scale for layer 3
                enc16(sv, hout + (size_t)node * 32 + c2 * 16);
                #pragma unroll
                for (int jj = 0; jj < 16; jj++) { bs[jj] += hv[jj]; bq[jj] += hv[jj] * hv[jj]; }
            } else {
                enc16(hv, hout + (size_t)node * 32 + c2 * 16);          // raw h3 for head
                float rs = 0.f;
                #pragma unroll
                for (int jj = 0; jj < 16; jj++) rs += hv[jj];
                rs += __shfl_xor(rs, 1, 64);
                if (c2 == 0) { rowsum[node] = rs; lmax = fmaxf(lmax, rs); }
            }
        }
        __syncthreads();
    }
    if (MODE == 0) {
        #pragma unroll
        for (int m = 2; m < 64; m <<= 1) {
            #pragma unroll
            for (int j = 0; j < 16; j++) {
                bs[j] += __shfl_xor(bs[j], m, 64);
                bq[j] += __shfl_xor(bq[j], m, 64);
            }
        }
        __shared__ float ssum[4][32], ssq[4][32];
        if ((lane >> 1) == 0) {
            #pragma unroll
            for (int j = 0; j < 16; j++) { ssum[wave][c2 * 16 + j] = bs[j]; ssq[wave][c2 * 16 + j] = bq[j]; }
        }
        __syncthreads();
        if (tid < 32) {
            atomicAdd(&osum[tid], ssum[0][tid] + ssum[1][tid] + ssum[2][tid] + ssum[3][tid]);
            atomicAdd(&osq[tid],  ssq[0][tid] + ssq[1][tid] + ssq[2][tid] + ssq[3][tid]);
        }
    } else {
        #pragma unroll
        for (int m = 1; m < 64; m <<= 1) lmax = fmaxf(lmax, __shfl_xor(lmax, m, 64));
        __shared__ float lm[4];
        if (lane == 0) lm[wave] = lmax;
        __syncthreads();
        if (tid == 0) {
            float m = fmaxf(fmaxf(lm[0], lm[1]), fmaxf(lm[2], lm[3]));
            uint u = __float_as_uint(m);
            uint key = (u & 0x80000000u) ? ~u : (u | 0x80000000u);
            atomicMax(maxkey, key);
        }
    }
}

// ---------------- fused heads: candidate scores + softmax pooling + graph head ----------------
__global__ __launch_bounds__(256) void head_kernel(const uchar* hb, const int* nt,
                                                   const uint* pos, const float* Wc1,
                                                   const float* bc1, const float* Wc2,
                                                   const float* bc2, const float* rowsum,
                                                   const uint* maxkey, float* gvec, float* Zp,
                                                   uint* ticket, const float* Wd1,
                                                   const float* bd1, const float* Wd2,
                                                   const float* bd2, float* out, int n, int C) {
    __shared__ float W1s[512], b1s[16], W2s[16];
    __shared__ float ls[256];
    __shared__ float ge[32], tt[16];
    __shared__ int lastflag;
    int tid = threadIdx.x;
    for (int t = tid; t < 512; t += 256) W1s[t] = Wc1[t];
    if (tid < 16) { b1s[tid] = bc1[tid]; W2s[tid] = Wc2[tid]; }
    __syncthreads();
    // Part A: candidate scores
    int i = blockIdx.x * 256 + tid;
    if (i < n && nt[i] == 0) {
        float hv[32];
        dec32(hb + (size_t)i * 32, hv);
        float s = bc2[0];
        #pragma unroll
        for (int j = 0; j < 16; j++) {
            float u = b1s[j];
            #pragma unroll
            for (int k = 0; k < 32; k++) u += hv[k] * W1s[k * 16 + j];
            s += fmaxf(u, 0.f) * W2s[j];
        }
        s = fminf(fmaxf(s, -1000.f), 1000.f);
        uint p = pos[i];
        if (p < (uint)C) {
            out[p] = s;
            out[C + 1 + p] = (float)i;
        }
    }
    // Part B: pooling partials (lane reads one fp8 channel)
    uint key = *maxkey;
    float M = 0.f;
    if (key != 0u) M = (key & 0x80000000u) ? __uint_as_float(key ^ 0x80000000u) : __uint_as_float(~key);
    int lane = tid & 31, grp = tid >> 5;
    int stride = gridDim.x * 8;
    float accZ = 0.f, accg = 0.f;
    for (int node = blockIdx.x * 8 + grp; node < n; node += stride) {
        float ew = __expf(rowsum[node] - M);
        accg += fp82f(hb[(size_t)node * 32 + lane]) * ew;
        if (lane == 0) accZ += ew;
    }
    ls[tid] = accg;
    __syncthreads();
    if (tid < 32) {
        float a = 0.f;
        #pragma unroll
        for (int g = 0; g < 8; g++) a += ls[tid + 32 * g];
        atomicAdd(&gvec[tid], a);
    }
    __syncthreads();
    ls[tid] = (lane == 0) ? accZ : 0.f;
    __syncthreads();
    if (tid == 0) {
        float a = 0.f;
        for (int t = 0; t < 256; t += 32) a += ls[t];
        atomicAdd(Zp, a);
        __threadfence();
        uint old = atomicAdd(ticket, 1u);
        lastflag = (old == gridDim.x - 1) ? 1 : 0;
    }
    __syncthreads();
    // Part C: last block computes graph head
    if (lastflag) {
        __threadfence();
        if (tid < 32) ge[tid] = atomicAdd(&gvec[tid], 0.f);
        if (tid == 0) ls[0] = atomicAdd(Zp, 0.f);
        __syncthreads();
        float Zv = fmaxf(ls[0], 1e-30f);
        if (tid < 32) ge[tid] /= Zv;
        __syncthreads();
        if (tid < 16) {
            float s = bd1[tid];
            for (int k = 0; k < 32; k++) s += ge[k] * Wd1[k * 16 + tid];
            tt[tid] = fmaxf(s, 0.f);
        }
        __syncthreads();
        if (tid == 0) {
            float s = bd2[0];
            for (int j = 0; j < 16; j++) s += tt[j] * Wd2[j];
            out[C] = fminf(fmaxf(s, -1000.f), 1000.f);
        }
    }
}

// ---------------- host launch ----------------
extern "C" void kernel_launch(void* const* d_in, const int* in_sizes, int n_in,
                              void* d_out, int out_size, void* d_ws, size_t ws_size,
                              hipStream_t stream) {
    const float* x   = (const float*)d_in[0];
    const int*   ei  = (const int*)d_in[1];
    const int*   nt  = (const int*)d_in[2];
    const float* W1  = (const float*)d_in[3];  const float* b1  = (const float*)d_in[4];
    const float* W2  = (const float*)d_in[5];  const float* b2  = (const float*)d_in[6];
    const float* W3  = (const float*)d_in[7];  const float* b3  = (const float*)d_in[8];
    const float* g1  = (const float*)d_in[9];  const float* be1 = (const float*)d_in[10];
    const float* g2  = (const float*)d_in[11]; const float* be2 = (const float*)d_in[12];
    const float* Wc1 = (const float*)d_in[13]; const float* bc1 = (const float*)d_in[14];
    const float* Wc2 = (const float*)d_in[15]; const float* bc2 = (const float*)d_in[16];
    const float* Wd1 = (const float*)d_in[17]; const float* bd1 = (const float*)d_in[18];
    const float* Wd2 = (const float*)d_in[19]; const float* bd2 = (const float*)d_in[20];

    const int N = in_sizes[0] / 3;
    const int E = in_sizes[1] / 2;
    const int C = (out_size - 1) / 2;
    const int* e_src = ei;
    const int* e_dst = ei + E;
    float* out = (float*)d_out;

    // bucket geometry: nodes/bucket = 1<<shift, NB <= 256 (packing needs N < 2^17)
    int shift = 9;
    while (((N + (1 << shift) - 1) >> shift) > NB_MAX) shift++;
    const int NB = (N + (1 << shift) - 1) >> shift;

    // ---- workspace carve-up (~14 MB) ----
    char* w = (char*)d_ws;
    auto alloc = [&](size_t bytes) { void* p = (void*)w; w += (bytes + 255) & ~(size_t)255; return p; };
    float*    stats  = (float*)alloc(256 * 4);     // zeroed
    uint*     bcnt   = (uint*)alloc(NB_MAX * 4);   // zeroed
    uint*     bcand  = (uint*)alloc(NB_MAX * 4);   // zeroed
    uint*     alloc0 = (uint*)alloc(NB_MAX * 4);   // zeroed
    size_t zero_bytes = (size_t)((char*)w - (char*)stats);
    float*    dinv   = (float*)alloc((size_t)N * 4);
    uint*     csr_off= (uint*)alloc((size_t)(N + 1) * 4);
    uint*     cand_pos=(uint*)alloc((size_t)N * 4);
    float*    rowsum = (float*)alloc((size_t)N * 4);
    float*    Sbuf   = (float*)alloc((size_t)N * 4);
    int*      csr_src= (int*)alloc((size_t)E * 4);
    uint*     staging= (uint*)alloc((size_t)E * 4);
    uchar*    zb     = (uchar*)alloc((size_t)N * 32);
    uchar*    hb     = (uchar*)alloc((size_t)N * 32);
    // xs (N*16B float4) aliases zb (dead until aggbn<0> writes h2 into zb)
    float4*   xs     = (float4*)zb;

    float* sum1 = stats;       float* sq1 = stats + 32;
    float* sum2 = stats + 64;  float* sq2 = stats + 96;
    float* gvec = stats + 128; float* Zp  = stats + 160;
    uint* maxkey = (uint*)(stats + 161);
    uint* ticket = (uint*)(stats + 162);
    uint* gt1 = (uint*)(stats + 163);
    uint* gt2 = (uint*)(stats + 164);
    uint* gt3 = (uint*)(stats + 165);

    hipMemsetAsync(stats, 0, zero_bytes, stream);

    const int gN   = (N + 255) / 256;
    const int gPar = (E + 2047) / 2048;
    int gAgg = (N + 127) / 128;
    if (gAgg > 512) gAgg = 512;                     // R4 verdict: 512 > 782 (MSHR-bound, not wave-starved)
    const float inv_n = 1.0f / (float)N;

    // ---- CSR build (XCD-local two-phase counting sort, packed staging) ----
    hipLaunchKernelGGL(bucket_hist_kernel, dim3(784), dim3(256), 0, stream, e_src, e_dst, nt, bcnt, bcand, E, N, NB, shift);
    hipLaunchKernelGGL(partition_kernel, dim3(gPar), dim3(256), 0, stream, e_src, e_dst, bcnt, alloc0, staging, E, N, shift);
    hipLaunchKernelGGL(local_csr_kernel, dim3(NB), dim3(256), 0, stream, staging, bcnt, bcand, nt,
                       x, csr_src, csr_off, cand_pos, dinv, xs, N, shift, NB);

    // ---- layer 1 (pair-per-node rank-3 aggregation + fused W1; writes pre-scaled h1 + S) ----
    hipLaunchKernelGGL(agg1_kernel, dim3(gAgg), dim3(256), 0, stream, (const float*)xs, csr_src, csr_off,
                       dinv, W1, b1, hb, Sbuf, N, sum1, sq1, gt1);

    // ---- layer 2: aggregate + BN1-fold + W2 ----
    hipLaunchKernelGGL((aggbn_kernel<0>), dim3(gAgg), dim3(256), 0, stream, hb, csr_src, csr_off,
                       dinv, Sbuf, sum1, sq1, g1, be1, W2, b2, zb, N, inv_n,
                       sum2, sq2, rowsum, maxkey, gt2);

    // ---- layer 3: aggregate + BN2-fold + W3 ----
    hipLaunchKernelGGL((aggbn_kernel<1>), dim3(gAgg), dim3(256), 0, stream, zb, csr_src, csr_off,
                       dinv, Sbuf, sum2, sq2, g2, be2, W3, b3, hb, N, inv_n,
                       sum1, sq1, rowsum, maxkey, gt3);

    // ---- fused heads ----
    hipLaunchKernelGGL(head_kernel, dim3(gN), dim3(256), 0, stream, hb, nt, cand_pos,
                       Wc1, bc1, Wc2, bc2, rowsum, maxkey, gvec, Zp, ticket,
                       Wd1, bd1, Wd2, bd2, out, N, C);
}

// Round 6
// 306.078 us; speedup vs baseline: 1.1322x; 1.0600x over previous
//
#include <hip/hip_runtime.h>

typedef unsigned int uint;
typedef unsigned char uchar;

#define NB_MAX 256      // max buckets
#define NPB_MAX 2048    // max nodes per bucket

#if defined(__has_builtin)
#if __has_builtin(__builtin_amdgcn_cvt_pk_f32_fp8) && __has_builtin(__builtin_amdgcn_cvt_pk_fp8_f32)
#define HW_FP8 1
#endif
#endif

typedef __attribute__((ext_vector_type(2))) float v2f;

// ---------------- fp8 e4m3 codecs (internal z/h storage) ----------------
static __device__ __forceinline__ uint f2fp8_sw(float v) {
    v = fminf(fmaxf(v, -448.f), 448.f);
    uint u = __float_as_uint(v);
    uint s = (u >> 24) & 0x80u;
    uint mag = u & 0x7FFFFFFFu;
    uint r = mag + 0x7FFFFu + ((mag >> 20) & 1u);     // RNE to 3 mantissa bits
    if (r < 0x3C800000u) return s;                    // below 2^-6 -> ±0
    uint e8 = (r - 0x3C000000u) >> 20;
    return s | min(e8, 0x7Eu);
}
static __device__ __forceinline__ float fp82f(uint b) {
    uint mag = b & 0x7Fu;
    uint bits = ((b & 0x80u) << 24) | ((mag << 20) + 0x3C000000u);
    return mag ? __uint_as_float(bits) : 0.f;
}
static __device__ __forceinline__ void dec8(uint2 v, float* o) {
#ifdef HW_FP8
    v2f a = __builtin_amdgcn_cvt_pk_f32_fp8((int)v.x, false);
    v2f b = __builtin_amdgcn_cvt_pk_f32_fp8((int)v.x, true);
    v2f c = __builtin_amdgcn_cvt_pk_f32_fp8((int)v.y, false);
    v2f d = __builtin_amdgcn_cvt_pk_f32_fp8((int)v.y, true);
    o[0]=a.x; o[1]=a.y; o[2]=b.x; o[3]=b.y;
    o[4]=c.x; o[5]=c.y; o[6]=d.x; o[7]=d.y;
#else
    o[0]=fp82f(v.x&0xFF); o[1]=fp82f((v.x>>8)&0xFF); o[2]=fp82f((v.x>>16)&0xFF); o[3]=fp82f(v.x>>24);
    o[4]=fp82f(v.y&0xFF); o[5]=fp82f((v.y>>8)&0xFF); o[6]=fp82f((v.y>>16)&0xFF); o[7]=fp82f(v.y>>24);
#endif
}
static __device__ __forceinline__ uint2 enc8(const float* o) {
#ifdef HW_FP8
    int rx = __builtin_amdgcn_cvt_pk_fp8_f32(o[0], o[1], 0, false);
    rx = __builtin_amdgcn_cvt_pk_fp8_f32(o[2], o[3], rx, true);
    int ry = __builtin_amdgcn_cvt_pk_fp8_f32(o[4], o[5], 0, false);
    ry = __builtin_amdgcn_cvt_pk_fp8_f32(o[6], o[7], ry, true);
    return make_uint2((uint)rx, (uint)ry);
#else
    uint2 r;
    r.x = f2fp8_sw(o[0]) | (f2fp8_sw(o[1])<<8) | (f2fp8_sw(o[2])<<16) | (f2fp8_sw(o[3])<<24);
    r.y = f2fp8_sw(o[4]) | (f2fp8_sw(o[5])<<8) | (f2fp8_sw(o[6])<<16) | (f2fp8_sw(o[7])<<24);
    return r;
#endif
}
static __device__ __forceinline__ void dec32(const uchar* row, float* o) {
    const uint4* r4 = (const uint4*)row;
    uint4 A = r4[0], B = r4[1];
    dec8(make_uint2(A.x,A.y), o); dec8(make_uint2(A.z,A.w), o+8);
    dec8(make_uint2(B.x,B.y), o+16); dec8(make_uint2(B.z,B.w), o+24);
}

// ---------------- wave-level inclusive scan (64 lanes) ----------------
static __device__ __forceinline__ unsigned wave_incl_scan(unsigned v) {
    int lane = threadIdx.x & 63;
    #pragma unroll
    for (int d = 1; d < 64; d <<= 1) {
        unsigned t = (unsigned)__shfl_up((int)v, d, 64);
        if (lane >= d) v += t;
    }
    return v;
}

// exclusive block scan: in[0..n) -> out[0..n), n <= 2048, 256 threads, wscr = shared[4]
static __device__ void block_excl_scan(const uint* in, uint* out, int n, uint* wscr) {
    int tid = threadIdx.x;
    int lane = tid & 63, wid = tid >> 6;
    int base = tid * 8;
    uint v[8], pre[8], s = 0;
    #pragma unroll
    for (int k = 0; k < 8; k++) v[k] = (base + k < n) ? in[base + k] : 0u;
    #pragma unroll
    for (int k = 0; k < 8; k++) { pre[k] = s; s += v[k]; }
    uint is = wave_incl_scan(s);
    __syncthreads();
    if (lane == 63) wscr[wid] = is;
    __syncthreads();
    uint woff = 0;
    for (int wI = 0; wI < wid; wI++) woff += wscr[wI];
    uint excl = is - s + woff;
    #pragma unroll
    for (int k = 0; k < 8; k++) if (base + k < n) out[base + k] = excl + pre[k];
    __syncthreads();
}

// ---------------- phase 1: per-bucket edge & candidate histograms ----------------
__global__ __launch_bounds__(256) void bucket_hist_kernel(const int* src, const int* dst,
                                                          const int* nt, uint* bcnt, uint* bcand,
                                                          int E, int N, int NB, int shift) {
    __shared__ uint bh[NB_MAX], ch[NB_MAX];
    int tid = threadIdx.x;
    bh[tid] = 0; ch[tid] = 0;
    __syncthreads();
    int gs = gridDim.x * 256;
    for (int i = blockIdx.x * 256 + tid; i < E; i += gs) {
        int d = dst[i], s = src[i];
        if ((uint)d < (uint)N && (uint)s < (uint)N) atomicAdd(&bh[d >> shift], 1u);
    }
    for (int i = blockIdx.x * 256 + tid; i < N; i += gs) {
        if (nt[i] == 0) atomicAdd(&ch[i >> shift], 1u);
    }
    __syncthreads();
    if (bh[tid]) atomicAdd(&bcnt[tid], bh[tid]);
    if (ch[tid]) atomicAdd(&bcand[tid], ch[tid]);
}

// ---------------- phase 2: partition edges into bucket-contiguous packed staging ----------------
// staging entry: (dst_local << 17) | src   (requires N < 2^17, shift <= 15)
__global__ __launch_bounds__(256) void partition_kernel(const int* src, const int* dst,
                                                        const uint* bcnt, uint* alloc0,
                                                        uint* staging, int E, int N, int shift) {
    __shared__ uint bbase_s[NB_MAX];
    __shared__ uint lh[NB_MAX], gb[NB_MAX];
    __shared__ uint ws4[4];
    int tid = threadIdx.x;
    int lane = tid & 63, wid = tid >> 6;
    uint a = bcnt[tid];
    uint ia = wave_incl_scan(a);
    if (lane == 63) ws4[wid] = ia;
    __syncthreads();
    uint off = 0;
    for (int wI = 0; wI < wid; wI++) off += ws4[wI];
    bbase_s[tid] = ia - a + off;
    lh[tid] = 0;
    __syncthreads();
    int base = blockIdx.x * 2048;
    uint mask = (1u << shift) - 1u;
    int breg[8];
    uint rreg[8], pk8[8];
    #pragma unroll
    for (int k = 0; k < 8; k++) {
        int e = base + k * 256 + tid;
        breg[k] = -1;
        if (e < E) {
            int s = src[e], d = dst[e];
            if ((uint)d < (uint)N && (uint)s < (uint)N) {
                int b = d >> shift;
                pk8[k] = (((uint)d & mask) << 17) | (uint)s;
                breg[k] = b;
                rreg[k] = atomicAdd(&lh[b], 1u);
            }
        }
    }
    __syncthreads();
    gb[tid] = lh[tid] ? (bbase_s[tid] + atomicAdd(&alloc0[tid], lh[tid])) : 0u;
    __syncthreads();
    #pragma unroll
    for (int k = 0; k < 8; k++) {
        if (breg[k] >= 0)
            staging[gb[breg[k]] + rreg[k]] = pk8[k];
    }
}

// ---------------- phase 3: per-bucket counting sort + csr_off/dinv/cand_pos + xs rows ----------------
// xs row = (x*dinv, dinv) so layer-1 agg also produces S = dinv_i + sum dinv_j in lane c4==3
__global__ __launch_bounds__(256) void local_csr_kernel(const uint* staging, const uint* bcnt,
                                                        const uint* bcand, const int* nt,
                                                        const float* x,
                                                        int* csr_src, uint* csr_off, uint* cand_pos,
                                                        float* dinv, float4* xs,
                                                        int N, int shift, int NB) {
    __shared__ uint deg[NPB_MAX];
    __shared__ uint ofs[NPB_MAX];
    __shared__ uint ws4[4];
    __shared__ uint sb[4];        // ebase, eend, cb
    int b = blockIdx.x, tid = threadIdx.x;
    int lane = tid & 63, wid = tid >> 6;
    uint a = bcnt[tid];
    uint ia = wave_incl_scan(a);
    if (lane == 63) ws4[wid] = ia;
    __syncthreads();
    uint off = 0;
    for (int wI = 0; wI < wid; wI++) off += ws4[wI];
    if (tid == b) { sb[0] = ia - a + off; sb[1] = ia + off; }
    __syncthreads();
    uint c = bcand[tid];
    uint ic = wave_incl_scan(c);
    if (lane == 63) ws4[wid] = ic;
    __syncthreads();
    uint offc = 0;
    for (int wI = 0; wI < wid; wI++) offc += ws4[wI];
    if (tid == b) sb[2] = ic - c + offc;
    __syncthreads();
    uint ebase = sb[0], eend = sb[1], cb = sb[2];
    int nbase = b << shift;
    int ncount = min(1 << shift, N - nbase);
    for (int i = tid; i < ncount; i += 256) deg[i] = 0;
    __syncthreads();
    for (uint p = ebase + tid; p < eend; p += 256)
        atomicAdd(&deg[staging[p] >> 17], 1u);
    __syncthreads();
    block_excl_scan(deg, ofs, ncount, ws4);
    for (int i = tid; i < ncount; i += 256)
        csr_off[nbase + i] = ebase + ofs[i];
    if (b == NB - 1 && tid == 0) csr_off[N] = eend;
    // fused dinv + xs = (x * dinv, dinv)  (deg still intact)
    for (int i = tid; i < ncount; i += 256) {
        int g = nbase + i;
        float di = rsqrtf((float)(deg[i] + 1u));   // +1 self loop
        dinv[g] = di;
        xs[g] = make_float4(x[3*g] * di, x[3*g+1] * di, x[3*g+2] * di, di);
    }
    __syncthreads();
    for (int i = tid; i < ncount; i += 256) deg[i] = 0;   // reuse as running counters
    __syncthreads();
    for (uint p = ebase + tid; p < eend; p += 256) {
        uint pkv = staging[p];
        uint dl = pkv >> 17;
        uint pos = ebase + ofs[dl] + atomicAdd(&deg[dl], 1u);
        csr_src[pos] = (int)(pkv & 0x1FFFFu);
    }
    __syncthreads();
    for (int i = tid; i < ncount; i += 256) deg[i] = (nt[nbase + i] == 0) ? 1u : 0u;
    __syncthreads();
    block_excl_scan(deg, ofs, ncount, ws4);
    for (int i = tid; i < ncount; i += 256) cand_pos[nbase + i] = cb + ofs[i];
}

// ---------------- layer-1 aggregate: rank-3 trick, quad-per-node, 16-deep load batches ----------------
// Writes hb = fp8(dinv_i * h1_i) (pre-scaled), Sbuf[i] = closed-nbhd dinv sum, stats over RAW h1.
__global__ __launch_bounds__(256) void agg1_kernel(const float* xs, const int* csr_src,
                                                   const uint* csr_off, const float* dinv,
                                                   const float* W1, const float* b1, uchar* hb,
                                                   float* Sbuf, int n,
                                                   float* stats_sum, float* stats_sq,
                                                   uint* gt) {
    const int tid = threadIdx.x;
    const int wave = tid >> 6;
    const int lane = tid & 63;
    const int c4 = lane & 3;
    const int slot = lane >> 2;
    const int qlead = lane & ~3;
    __shared__ float W1s[96];
    __shared__ uint s_lt, s_chunk;
    if (tid < 96) W1s[tid] = W1[tid];
    const float2* xs2 = (const float2*)xs;   // lane c4 reads float2 {2*c4, 2*c4+1} of the 4-float row? no:
    // xs row is float4; quad lane c4 reads component c4 as before (8B float2 would misalign per-lane).
    float bv[8];
    #pragma unroll
    for (int j = 0; j < 8; j++) bv[j] = b1[c4 * 8 + j];
    float bs[8], bq[8];
    #pragma unroll
    for (int j = 0; j < 8; j++) { bs[j] = 0.f; bq[j] = 0.f; }
    __syncthreads();
    (void)xs2;
    while (true) {
        if (tid == 0) s_chunk = atomicAdd(gt, 1u);
        __syncthreads();
        uint cbase = s_chunk * 128u;
        if (cbase >= (uint)n) break;
        uint avail = min((uint)n - cbase, 128u);
        if (tid == 0) s_lt = 0u;
        __syncthreads();
        while (true) {
            uint li = 0;
            if (c4 == 0) li = atomicAdd(&s_lt, 1u);
            li = (uint)__shfl((int)li, qlead, 64);
            if (li >= avail) break;
            uint node = cbase + li;
            uint s = csr_off[node], e = csr_off[node + 1];
            float acc = xs[(size_t)node * 4 + c4];     // self loop (xs has dinv folded; .w = dinv)
            for (uint p = s; p < e; p += 16) {
                uint idx[16];
                float wg[16];
                #pragma unroll
                for (int j = 0; j < 16; j++) {
                    uint q = p + (uint)j;
                    uint qc = min(q, e - 1u);
                    idx[j] = (uint)csr_src[qc];
                    wg[j] = (q < e) ? 1.f : 0.f;
                }
                float xr[16];                          // all 16 gathers in flight before any FMA
                #pragma unroll
                for (int j = 0; j < 16; j++)
                    xr[j] = xs[(size_t)idx[j] * 4 + c4];
                #pragma unroll
                for (int j = 0; j < 16; j++)
                    acc = fmaf(wg[j], xr[j], acc);
            }
            if (c4 == 3) Sbuf[node] = acc;             // S_i (raw sum of dinv over closed nbhd)
            float di = dinv[node];
            float u = di * acc;
            float u0 = __shfl(u, qlead, 64);
            float u1 = __shfl(u, qlead + 1, 64);
            float u2 = __shfl(u, qlead + 2, 64);
            float hv[8], sv[8];
            #pragma unroll
            for (int j = 0; j < 8; j++) {
                int ch = c4 * 8 + j;
                float o = u0 * W1s[ch] + u1 * W1s[32 + ch] + u2 * W1s[64 + ch] + bv[j];
                hv[j] = fmaxf(o, 0.f);
                sv[j] = di * hv[j];                    // pre-scaled storage
            }
            *(uint2*)(hb + (size_t)node * 32 + c4 * 8) = enc8(sv);
            #pragma unroll
            for (int j = 0; j < 8; j++) { bs[j] += hv[j]; bq[j] += hv[j] * hv[j]; }
        }
        __syncthreads();
    }
    #pragma unroll
    for (int m = 4; m < 64; m <<= 1) {
        #pragma unroll
        for (int j = 0; j < 8; j++) {
            bs[j] += __shfl_xor(bs[j], m, 64);
            bq[j] += __shfl_xor(bq[j], m, 64);
        }
    }
    __shared__ float ssum[4][32], ssq[4][32];
    if (slot == 0) {
        #pragma unroll
        for (int j = 0; j < 8; j++) { ssum[wave][c4 * 8 + j] = bs[j]; ssq[wave][c4 * 8 + j] = bq[j]; }
    }
    __syncthreads();
    if (tid < 32) {
        atomicAdd(&stats_sum[tid], ssum[0][tid] + ssum[1][tid] + ssum[2][tid] + ssum[3][tid]);
        atomicAdd(&stats_sq[tid],  ssq[0][tid] + ssq[1][tid] + ssq[2][tid] + ssq[3][tid]);
    }
}

// ---------------- fused aggregate + BN-fold + W transform (layers 2/3), quad, 16-deep batches ----------------
// Input hin rows are fp8(dinv_m * h_m). Aggregate H_i = sum over closed nbhd (plain sum),
// then out = relu(dinv_i * (W^T(a o H_i) + cs*S_i) + bias).
// MODE 0: store pre-scaled fp8(dinv_i*out) + BN stats of raw out (layer 2).
// MODE 1: store RAW fp8(out) + rowsum/maxkey (layer 3, consumed by head).
template<int MODE>
__global__ __launch_bounds__(256) void aggbn_kernel(const uchar* hin, const int* csr_src,
                                                    const uint* csr_off, const float* dinv,
                                                    const float* Sbuf,
                                                    const float* stats_sum, const float* stats_sq,
                                                    const float* g, const float* be,
                                                    const float* W, const float* bias,
                                                    uchar* hout, int n, float inv_n,
                                                    float* osum, float* osq,
                                                    float* rowsum, uint* maxkey, uint* gt) {
    const int tid = threadIdx.x;
    const int wave = tid >> 6;
    const int lane = tid & 63;
    const int c4 = lane & 3;
    const int slot = lane >> 2;
    const int qlead = lane & ~3;
    __shared__ float Ws[1024];
    __shared__ float cs[32], a_s[32], d_s[32];
    __shared__ uint s_lt, s_chunk;
    if (tid < 32) {
        float mu = stats_sum[tid] * inv_n;
        float var = fmaxf(stats_sq[tid] * inv_n - mu * mu, 0.f);
        float a = g[tid] * rsqrtf(var + 1e-5f);
        a_s[tid] = a;
        d_s[tid] = be[tid] - mu * a;
    }
    __syncthreads();
    for (int t = tid; t < 1024; t += 256) Ws[t] = a_s[t >> 5] * W[t];
    if (tid < 32) {
        float c = 0.f;
        for (int k = 0; k < 32; k++) c += d_s[k] * W[k * 32 + tid];
        cs[tid] = c;
    }
    float bv[8];
    #pragma unroll
    for (int j = 0; j < 8; j++) bv[j] = bias[c4 * 8 + j];
    float bs[8], bq[8];
    if (MODE == 0) {
        #pragma unroll
        for (int j = 0; j < 8; j++) { bs[j] = 0.f; bq[j] = 0.f; }
    }
    float lmax = -3.0e38f;
    __syncthreads();
    while (true) {
        if (tid == 0) s_chunk = atomicAdd(gt, 1u);
        __syncthreads();
        uint cbase = s_chunk * 128u;
        if (cbase >= (uint)n) break;
        uint avail = min((uint)n - cbase, 128u);
        if (tid == 0) s_lt = 0u;
        __syncthreads();
        while (true) {
            uint li = 0;
            if (c4 == 0) li = atomicAdd(&s_lt, 1u);
            li = (uint)__shfl((int)li, qlead, 64);
            if (li >= avail) break;
            uint node = cbase + li;
            uint s = csr_off[node], e = csr_off[node + 1];
            float acc[8];
            dec8(*(const uint2*)(hin + (size_t)node * 32 + c4 * 8), acc);   // self (pre-scaled)
            for (uint p = s; p < e; p += 16) {
                uint idx[16];
                float wg[16];
                #pragma unroll
                for (int j = 0; j < 16; j++) {
                    uint q = p + (uint)j;
                    uint qc = min(q, e - 1u);
                    idx[j] = (uint)csr_src[qc];
                    wg[j] = (q < e) ? 1.f : 0.f;
                }
                uint2 rw[16];                          // all 16 row gathers in flight before decode/FMA
                #pragma unroll
                for (int j = 0; j < 16; j++)
                    rw[j] = *(const uint2*)(hin + (size_t)idx[j] * 32 + c4 * 8);
                #pragma unroll
                for (int j = 0; j < 16; j++) {
                    float t[8];
                    dec8(rw[j], t);
                    #pragma unroll
                    for (int cI = 0; cI < 8; cI++) acc[cI] = fmaf(wg[j], t[cI], acc[cI]);
                }
            }
            // gather full 32-channel H_i across the quad (32 shuffles)
            float af[32];
            #pragma unroll
            for (int cc = 0; cc < 4; cc++) {
                #pragma unroll
                for (int r = 0; r < 8; r++)
                    af[cc * 8 + r] = __shfl(acc[r], qlead + cc, 64);
            }
            float di = dinv[node];
            float Sv = Sbuf[node];
            float hv[8], sv[8];
            #pragma unroll
            for (int jj = 0; jj < 8; jj++) {
                int j = c4 * 8 + jj;
                float t = cs[j] * Sv;
                #pragma unroll
                for (int k = 0; k < 32; k++) t = fmaf(Ws[k * 32 + j], af[k], t);
                hv[jj] = fmaxf(fmaf(di, t, bv[jj]), 0.f);
            }
            if (MODE == 0) {
                #pragma unroll
                for (int jj = 0; jj < 8; jj++) sv[jj] = di * hv[jj];   // pre-scale for layer 3
                *(uint2*)(hout + (size_t)node * 32 + c4 * 8) = enc8(sv);
                #pragma unroll
                for (int jj = 0; jj < 8; jj++) { bs[jj] += hv[jj]; bq[jj] += hv[jj] * hv[jj]; }
            } else {
                *(uint2*)(hout + (size_t)node * 32 + c4 * 8) = enc8(hv);  // raw h3 for head
                float rs = ((hv[0] + hv[1]) + (hv[2] + hv[3])) + ((hv[4] + hv[5]) + (hv[6] + hv[7]));
                rs += __shfl_xor(rs, 1, 64);
                rs += __shfl_xor(rs, 2, 64);
                if (c4 == 0) { rowsum[node] = rs; lmax = fmaxf(lmax, rs); }
            }
        }
        __syncthreads();
    }
    if (MODE == 0) {
        #pragma unroll
        for (int m = 4; m < 64; m <<= 1) {
            #pragma unroll
            for (int j = 0; j < 8; j++) {
                bs[j] += __shfl_xor(bs[j], m, 64);
                bq[j] += __shfl_xor(bq[j], m, 64);
            }
        }
        __shared__ float ssum[4][32], ssq[4][32];
        if (slot == 0) {
            #pragma unroll
            for (int j = 0; j < 8; j++) { ssum[wave][c4 * 8 + j] = bs[j]; ssq[wave][c4 * 8 + j] = bq[j]; }
        }
        __syncthreads();
        if (tid < 32) {
            atomicAdd(&osum[tid], ssum[0][tid] + ssum[1][tid] + ssum[2][tid] + ssum[3][tid]);
            atomicAdd(&osq[tid],  ssq[0][tid] + ssq[1][tid] + ssq[2][tid] + ssq[3][tid]);
        }
    } else {
        #pragma unroll
        for (int m = 1; m < 64; m <<= 1) lmax = fmaxf(lmax, __shfl_xor(lmax, m, 64));
        __shared__ float lm[4];
        if (lane == 0) lm[wave] = lmax;
        __syncthreads();
        if (tid == 0) {
            float m = fmaxf(fmaxf(lm[0], lm[1]), fmaxf(lm[2], lm[3]));
            uint u = __float_as_uint(m);
            uint key = (u & 0x80000000u) ? ~u : (u | 0x80000000u);
            atomicMax(maxkey, key);
        }
    }
}

// ---------------- fused heads: candidate scores + softmax pooling + graph head ----------------
__global__ __launch_bounds__(256) void head_kernel(const uchar* hb, const int* nt,
                                                   const uint* pos, const float* Wc1,
                                                   const float* bc1, const float* Wc2,
                                                   const float* bc2, const float* rowsum,
                                                   const uint* maxkey, float* gvec, float* Zp,
                                                   uint* ticket, const float* Wd1,
                                                   const float* bd1, const float* Wd2,
                                                   const float* bd2, float* out, int n, int C) {
    __shared__ float W1s[512], b1s[16], W2s[16];
    __shared__ float ls[256];
    __shared__ float ge[32], tt[16];
    __shared__ int lastflag;
    int tid = threadIdx.x;
    for (int t = tid; t < 512; t += 256) W1s[t] = Wc1[t];
    if (tid < 16) { b1s[tid] = bc1[tid]; W2s[tid] = Wc2[tid]; }
    __syncthreads();
    // Part A: candidate scores
    int i = blockIdx.x * 256 + tid;
    if (i < n && nt[i] == 0) {
        float hv[32];
        dec32(hb + (size_t)i * 32, hv);
        float s = bc2[0];
        #pragma unroll
        for (int j = 0; j < 16; j++) {
            float u = b1s[j];
            #pragma unroll
            for (int k = 0; k < 32; k++) u += hv[k] * W1s[k * 16 + j];
            s += fmaxf(u, 0.f) * W2s[j];
        }
        s = fminf(fmaxf(s, -1000.f), 1000.f);
        uint p = pos[i];
        if (p < (uint)C) {
            out[p] = s;
            out[C + 1 + p] = (float)i;
        }
    }
    // Part B: pooling partials (lane reads one fp8 channel)
    uint key = *maxkey;
    float M = 0.f;
    if (key != 0u) M = (key & 0x80000000u) ? __uint_as_float(key ^ 0x80000000u) : __uint_as_float(~key);
    int lane = tid & 31, grp = tid >> 5;
    int stride = gridDim.x * 8;
    float accZ = 0.f, accg = 0.f;
    for (int node = blockIdx.x * 8 + grp; node < n; node += stride) {
        float ew = __expf(rowsum[node] - M);
        accg += fp82f(hb[(size_t)node * 32 + lane]) * ew;
        if (lane == 0) accZ += ew;
    }
    ls[tid] = accg;
    __syncthreads();
    if (tid < 32) {
        float a = 0.f;
        #pragma unroll
        for (int g = 0; g < 8; g++) a += ls[tid + 32 * g];
        atomicAdd(&gvec[tid], a);
    }
    __syncthreads();
    ls[tid] = (lane == 0) ? accZ : 0.f;
    __syncthreads();
    if (tid == 0) {
        float a = 0.f;
        for (int t = 0; t < 256; t += 32) a += ls[t];
        atomicAdd(Zp, a);
        __threadfence();
        uint old = atomicAdd(ticket, 1u);
        lastflag = (old == gridDim.x - 1) ? 1 : 0;
    }
    __syncthreads();
    // Part C: last block computes graph head
    if (lastflag) {
        __threadfence();
        if (tid < 32) ge[tid] = atomicAdd(&gvec[tid], 0.f);
        if (tid == 0) ls[0] = atomicAdd(Zp, 0.f);
        __syncthreads();
        float Zv = fmaxf(ls[0], 1e-30f);
        if (tid < 32) ge[tid] /= Zv;
        __syncthreads();
        if (tid < 16) {
            float s = bd1[tid];
            for (int k = 0; k < 32; k++) s += ge[k] * Wd1[k * 16 + tid];
            tt[tid] = fmaxf(s, 0.f);
        }
        __syncthreads();
        if (tid == 0) {
            float s = bd2[0];
            for (int j = 0; j < 16; j++) s += tt[j] * Wd2[j];
            out[C] = fminf(fmaxf(s, -1000.f), 1000.f);
        }
    }
}

// ---------------- host launch ----------------
extern "C" void kernel_launch(void* const* d_in, const int* in_sizes, int n_in,
                              void* d_out, int out_size, void* d_ws, size_t ws_size,
                              hipStream_t stream) {
    const float* x   = (const float*)d_in[0];
    const int*   ei  = (const int*)d_in[1];
    const int*   nt  = (const int*)d_in[2];
    const float* W1  = (const float*)d_in[3];  const float* b1  = (const float*)d_in[4];
    const float* W2  = (const float*)d_in[5];  const float* b2  = (const float*)d_in[6];
    const float* W3  = (const float*)d_in[7];  const float* b3  = (const float*)d_in[8];
    const float* g1  = (const float*)d_in[9];  const float* be1 = (const float*)d_in[10];
    const float* g2  = (const float*)d_in[11]; const float* be2 = (const float*)d_in[12];
    const float* Wc1 = (const float*)d_in[13]; const float* bc1 = (const float*)d_in[14];
    const float* Wc2 = (const float*)d_in[15]; const float* bc2 = (const float*)d_in[16];
    const float* Wd1 = (const float*)d_in[17]; const float* bd1 = (const float*)d_in[18];
    const float* Wd2 = (const float*)d_in[19]; const float* bd2 = (const float*)d_in[20];

    const int N = in_sizes[0] / 3;
    const int E = in_sizes[1] / 2;
    const int C = (out_size - 1) / 2;
    const int* e_src = ei;
    const int* e_dst = ei + E;
    float* out = (float*)d_out;

    // bucket geometry: nodes/bucket = 1<<shift, NB <= 256 (packing needs N < 2^17)
    int shift = 9;
    while (((N + (1 << shift) - 1) >> shift) > NB_MAX) shift++;
    const int NB = (N + (1 << shift) - 1) >> shift;

    // ---- workspace carve-up (~14 MB) ----
    char* w = (char*)d_ws;
    auto alloc = [&](size_t bytes) { void* p = (void*)w; w += (bytes + 255) & ~(size_t)255; return p; };
    float*    stats  = (float*)alloc(256 * 4);     // zeroed
    uint*     bcnt   = (uint*)alloc(NB_MAX * 4);   // zeroed
    uint*     bcand  = (uint*)alloc(NB_MAX * 4);   // zeroed
    uint*     alloc0 = (uint*)alloc(NB_MAX * 4);   // zeroed
    size_t zero_bytes = (size_t)((char*)w - (char*)stats);
    float*    dinv   = (float*)alloc((size_t)N * 4);
    uint*     csr_off= (uint*)alloc((size_t)(N + 1) * 4);
    uint*     cand_pos=(uint*)alloc((size_t)N * 4);
    float*    rowsum = (float*)alloc((size_t)N * 4);
    float*    Sbuf   = (float*)alloc((size_t)N * 4);
    int*      csr_src= (int*)alloc((size_t)E * 4);
    uint*     staging= (uint*)alloc((size_t)E * 4);
    uchar*    zb     = (uchar*)alloc((size_t)N * 32);
    uchar*    hb     = (uchar*)alloc((size_t)N * 32);
    // xs (N*16B float4) aliases zb (dead until aggbn<0> writes h2 into zb)
    float4*   xs     = (float4*)zb;

    float* sum1 = stats;       float* sq1 = stats + 32;
    float* sum2 = stats + 64;  float* sq2 = stats + 96;
    float* gvec = stats + 128; float* Zp  = stats + 160;
    uint* maxkey = (uint*)(stats + 161);
    uint* ticket = (uint*)(stats + 162);
    uint* gt1 = (uint*)(stats + 163);
    uint* gt2 = (uint*)(stats + 164);
    uint* gt3 = (uint*)(stats + 165);

    hipMemsetAsync(stats, 0, zero_bytes, stream);

    const int gN   = (N + 255) / 256;
    const int gPar = (E + 2047) / 2048;
    int gAgg = (N + 127) / 128;
    if (gAgg > 512) gAgg = 512;                     // R4 verdict: 512 best (782 regressed)
    const float inv_n = 1.0f / (float)N;

    // ---- CSR build (XCD-local two-phase counting sort, packed staging) ----
    hipLaunchKernelGGL(bucket_hist_kernel, dim3(784), dim3(256), 0, stream, e_src, e_dst, nt, bcnt, bcand, E, N, NB, shift);
    hipLaunchKernelGGL(partition_kernel, dim3(gPar), dim3(256), 0, stream, e_src, e_dst, bcnt, alloc0, staging, E, N, shift);
    hipLaunchKernelGGL(local_csr_kernel, dim3(NB), dim3(256), 0, stream, staging, bcnt, bcand, nt,
                       x, csr_src, csr_off, cand_pos, dinv, xs, N, shift, NB);

    // ---- layer 1 (rank-3 aggregation + fused W1; writes pre-scaled h1 + S) ----
    hipLaunchKernelGGL(agg1_kernel, dim3(gAgg), dim3(256), 0, stream, (const float*)xs, csr_src, csr_off,
                       dinv, W1, b1, hb, Sbuf, N, sum1, sq1, gt1);

    // ---- layer 2: aggregate + BN1-fold + W2 (gemm eliminated algebraically) ----
    hipLaunchKernelGGL((aggbn_kernel<0>), dim3(gAgg), dim3(256), 0, stream, hb, csr_src, csr_off,
                       dinv, Sbuf, sum1, sq1, g1, be1, W2, b2, zb, N, inv_n,
                       sum2, sq2, rowsum, maxkey, gt2);

    // ---- layer 3: aggregate + BN2-fold + W3 ----
    hipLaunchKernelGGL((aggbn_kernel<1>), dim3(gAgg), dim3(256), 0, stream, zb, csr_src, csr_off,
                       dinv, Sbuf, sum2, sq2, g2, be2, W3, b3, hb, N, inv_n,
                       sum1, sq1, rowsum, maxkey, gt3);

    // ---- fused heads ----
    hipLaunchKernelGGL(head_kernel, dim3(gN), dim3(256), 0, stream, hb, nt, cand_pos,
                       Wc1, bc1, Wc2, bc2, rowsum, maxkey, gvec, Zp, ticket,
                       Wd1, bd1, Wd2, bd2, out, N, C);
}